// Round 3
// baseline (3975.648 us; speedup 1.0000x reference)
//
#include <hip/hip_runtime.h>

#define N_SUB 200000
#define N_GR  4096
#define DIM   256
#define TCLS  10

// ---------------- helpers ----------------
__device__ __forceinline__ float block_reduce_sum_256(float v, float* red){
  int t = threadIdx.x;
  red[t] = v; __syncthreads();
  #pragma unroll
  for (int s = 128; s > 0; s >>= 1){
    if (t < s) red[t] += red[t+s];
    __syncthreads();
  }
  float r = red[0];
  __syncthreads();
  return r;
}

// ---------------- init: zero accumulators (must happen every call; graph replays) ----------------
__global__ void init_kernel(int* cnt_all, float* S, float* Se, int* counters, float* loss){
  int i = blockIdx.x*blockDim.x + threadIdx.x;
  if (i < N_GR) cnt_all[i] = 0;
  if (i < DIM){ S[i] = 0.f; Se[i] = 0.f; }
  if (i < 2) counters[i] = 0;
  if (i == 0) loss[0] = 0.f;
}

// ---------------- kernel A: fused MLP -> sigmoid mask + per-graph histogram ----------------
// block = 256 threads = 4 waves; 64 rows per block; wave q handles output cols [q*128, q*128+128)
// y[32] register accumulators per thread, 4 column groups of 32.
__global__ __launch_bounds__(256) void mask_gemm(
    const float* __restrict__ hsub, const float* __restrict__ W1,
    const float* __restrict__ b1, const float* __restrict__ W2,
    const float* __restrict__ b2, const int* __restrict__ s2g,
    float* __restrict__ mask_out, int* __restrict__ cnt_all)
{
  __shared__ float sred[256];
  const int tid = threadIdx.x;
  const int r = tid & 63;
  const int q = tid >> 6;
  const int row = blockIdx.x*64 + r;
  const float* __restrict__ arow = hsub + (size_t)row*DIM;
  float s = 0.f;
  for (int jg = 0; jg < 4; ++jg){
    const int jbase = q*128 + jg*32;
    float y[32];
    #pragma unroll
    for (int j = 0; j < 32; ++j) y[j] = b1[jbase+j];
    for (int kc = 0; kc < 16; ++kc){
      float a[16];
      #pragma unroll
      for (int kk = 0; kk < 4; ++kk){
        const float4 v = *reinterpret_cast<const float4*>(arow + kc*16 + kk*4);
        a[kk*4+0]=v.x; a[kk*4+1]=v.y; a[kk*4+2]=v.z; a[kk*4+3]=v.w;
      }
      #pragma unroll
      for (int k = 0; k < 16; ++k){
        const float4* __restrict__ wr =
            reinterpret_cast<const float4*>(W1 + (size_t)(kc*16+k)*512 + jbase);
        #pragma unroll
        for (int j4 = 0; j4 < 8; ++j4){
          const float4 w = wr[j4];
          y[j4*4+0] = fmaf(a[k], w.x, y[j4*4+0]);
          y[j4*4+1] = fmaf(a[k], w.y, y[j4*4+1]);
          y[j4*4+2] = fmaf(a[k], w.z, y[j4*4+2]);
          y[j4*4+3] = fmaf(a[k], w.w, y[j4*4+3]);
        }
      }
    }
    #pragma unroll
    for (int j = 0; j < 32; ++j) s += fmaxf(y[j], 0.f) * W2[jbase+j];
  }
  sred[tid] = s;
  __syncthreads();
  if (tid < 64){
    const float tot = sred[tid] + sred[tid+64] + sred[tid+128] + sred[tid+192] + b2[0];
    const float m = 1.f / (1.f + expf(-tot));
    const int rr = blockIdx.x*64 + tid;
    mask_out[rr] = m;
    atomicAdd(&cnt_all[s2g[rr]], 1);
  }
}

// ---------------- CSR build: scan + fill ----------------
__global__ __launch_bounds__(1024) void scan_kernel(const int* __restrict__ cnt,
                                                    int* __restrict__ offs,
                                                    int* __restrict__ cursor){
  __shared__ int buf[1024];
  const int t = threadIdx.x;
  const int c0 = cnt[t*4], c1 = cnt[t*4+1], c2 = cnt[t*4+2], c3 = cnt[t*4+3];
  const int s = c0+c1+c2+c3;
  buf[t] = s; __syncthreads();
  for (int d = 1; d < 1024; d <<= 1){
    int v = (t >= d) ? buf[t-d] : 0;
    __syncthreads();
    buf[t] += v;
    __syncthreads();
  }
  const int excl = buf[t] - s;
  const int o0 = excl, o1 = excl+c0, o2 = o1+c1, o3 = o2+c2;
  offs[t*4]=o0; offs[t*4+1]=o1; offs[t*4+2]=o2; offs[t*4+3]=o3;
  cursor[t*4]=o0; cursor[t*4+1]=o1; cursor[t*4+2]=o2; cursor[t*4+3]=o3;
  if (t == 1023) offs[4096] = buf[1023];
}

__global__ void fill_kernel(const int* __restrict__ s2g, int* __restrict__ cursor,
                            int* __restrict__ list){
  const int i = blockIdx.x*blockDim.x + threadIdx.x;
  if (i < N_SUB){
    const int g = s2g[i];
    const int p = atomicAdd(&cursor[g], 1);
    list[p] = i;
  }
}

// ---------------- kernel C: per-graph masked means + norms + nz + fused out-GEMM ----------------
__global__ __launch_bounds__(256) void graph_means(
    const float* __restrict__ hsub, const float* __restrict__ mask,
    const int* __restrict__ list, const int* __restrict__ offs,
    const float* __restrict__ hgraph, const float* __restrict__ Wc,
    const float* __restrict__ bc, float* __restrict__ hatA,
    float* __restrict__ S, float* __restrict__ Se,
    int* __restrict__ nzflags, int* __restrict__ counters,
    float* __restrict__ out)
{
  __shared__ float red[256];
  const int g = blockIdx.x;
  const int t = threadIdx.x;
  const int start = offs[g], end = offs[g+1];
  float sv = 0.f, sev = 0.f;
  int cv = 0, ce = 0;
  for (int p = start; p < end; ++p){
    const int i = list[p];
    const float m = mask[i];                 // broadcast
    const float v = hsub[(size_t)i*DIM + t]; // coalesced row
    if (m > 0.4f)      { sv  += v; cv++; }
    else if (m <= 0.3f){ sev += v; ce++; }
  }
  const float aligned = sv  / fmaxf((float)cv, 1.f);
  const float envv    = sev / fmaxf((float)ce, 1.f);
  const float an2  = block_reduce_sum_256(aligned*aligned, red);
  const float en2  = block_reduce_sum_256(envv*envv, red);
  const float nzpf = block_reduce_sum_256(aligned != 0.f ? 1.f : 0.f, red);
  const float nzef = block_reduce_sum_256(envv    != 0.f ? 1.f : 0.f, red);
  const bool nzp = nzpf > 0.f, nze = nzef > 0.f;
  const float an = fmaxf(sqrtf(an2), 1e-8f);
  const float en = fmaxf(sqrtf(en2), 1e-8f);
  const float ha = aligned / an;
  hatA[(size_t)g*DIM + t] = ha;
  atomicAdd(&S[t], ha);                 // zero rows contribute 0 anyway
  if (nze) atomicAdd(&Se[t], envv / en);
  if (t == 0){
    nzflags[g] = nzp ? 1 : 0;
    if (nzp) atomicAdd(&counters[0], 1);
    if (nze) atomicAdd(&counters[1], 1);
  }
  // fused: out[g] = concat(h_graph[g], aligned[g]) @ Wc + bc
  const float hg = hgraph[(size_t)g*DIM + t];
  #pragma unroll
  for (int c = 0; c < TCLS; ++c){
    const float part = hg*Wc[t*TCLS+c] + aligned*Wc[(DIM+t)*TCLS+c];
    const float tot = block_reduce_sum_256(part, red);
    if (t == 0) out[g*TCLS + c] = tot + bc[c];
  }
}

// ---------------- kernel D: contrastive loss via rank-1 identity ----------------
__global__ __launch_bounds__(256) void loss_kernel(
    const float* __restrict__ hatA, const float* __restrict__ S,
    const float* __restrict__ Se, const int* __restrict__ nzflags,
    const int* __restrict__ counters, float* __restrict__ loss)
{
  __shared__ float red[256];
  const int g = blockIdx.x, t = threadIdx.x;
  const float ha = hatA[(size_t)g*DIM + t];
  const float dS  = block_reduce_sum_256(ha*S[t], red);
  const float dSe = block_reduce_sum_256(ha*Se[t], red);
  if (t == 0){
    const int nzp_cnt = counters[0];
    const int nenv = counters[1];
    const float pos_num = fmaxf((float)(nzp_cnt - 1), 1.f);
    const float positive = (4096.f - dS) / pos_num;
    const float negative = ((float)nenv - dSe) / fmaxf((float)nenv, 1.f);
    float contrib = fmaxf(positive - negative + 1.f, 0.f);
    contrib *= (nzflags[g] ? 1.f : 0.f) * ((nenv > 0) ? 1.f : 0.f);
    atomicAdd(loss, contrib * (1.f/4096.f));
  }
}

// ---------------- launch ----------------
extern "C" void kernel_launch(void* const* d_in, const int* in_sizes, int n_in,
                              void* d_out, int out_size, void* d_ws, size_t ws_size,
                              hipStream_t stream) {
  const float* h_graph = (const float*)d_in[0];
  const float* h_sub   = (const float*)d_in[1];
  const float* W1      = (const float*)d_in[2];
  const float* b1      = (const float*)d_in[3];
  const float* W2      = (const float*)d_in[4];
  const float* b2      = (const float*)d_in[5];
  const float* Wc      = (const float*)d_in[6];
  const float* bc      = (const float*)d_in[7];
  const int*   s2g     = (const int*)d_in[8];

  float* out  = (float*)d_out;          // [4096,10]
  float* loss = out + N_GR*TCLS;        // scalar at 40960
  float* mask = loss + 1;               // [200000] at 40961

  // workspace layout (all 4-byte types)
  int* cnt_all  = (int*)d_ws;           // 4096
  int* offs     = cnt_all + N_GR;       // 4097
  int* cursor   = offs + N_GR + 1;      // 4096
  int* list     = cursor + N_GR;        // 200000
  int* nzflags  = list + N_SUB;         // 4096
  int* counters = nzflags + N_GR;       // 2
  float* S      = (float*)(counters + 2);  // 256
  float* Se     = S + DIM;                 // 256
  float* hatA   = Se + DIM;                // 4096*256

  hipLaunchKernelGGL(init_kernel, dim3(16), dim3(256), 0, stream,
                     cnt_all, S, Se, counters, loss);
  hipLaunchKernelGGL(mask_gemm, dim3(N_SUB/64), dim3(256), 0, stream,
                     h_sub, W1, b1, W2, b2, s2g, mask, cnt_all);
  hipLaunchKernelGGL(scan_kernel, dim3(1), dim3(1024), 0, stream,
                     cnt_all, offs, cursor);
  hipLaunchKernelGGL(fill_kernel, dim3((N_SUB+255)/256), dim3(256), 0, stream,
                     s2g, cursor, list);
  hipLaunchKernelGGL(graph_means, dim3(N_GR), dim3(256), 0, stream,
                     h_sub, mask, list, offs, h_graph, Wc, bc,
                     hatA, S, Se, nzflags, counters, out);
  hipLaunchKernelGGL(loss_kernel, dim3(N_GR), dim3(256), 0, stream,
                     hatA, S, Se, nzflags, counters, loss);
}

// Round 6
// 3561.311 us; speedup vs baseline: 1.1163x; 1.1163x over previous
//
#include <hip/hip_runtime.h>

#define N_SUB 200000
#define N_GR  4096
#define DIM   256
#define TCLS  10
#define LDS_STRIDE 260   // 256 + 4: keeps 16B alignment for b128, spreads banks

// ---------------- helpers ----------------
__device__ __forceinline__ float block_reduce_sum_256(float v, float* red){
  int t = threadIdx.x;
  red[t] = v; __syncthreads();
  #pragma unroll
  for (int s = 128; s > 0; s >>= 1){
    if (t < s) red[t] += red[t+s];
    __syncthreads();
  }
  float r = red[0];
  __syncthreads();
  return r;
}

// ---------------- init: zero accumulators (graph replays -> must run every call) ----------------
__global__ void init_kernel(int* cnt_all, float* S, float* Se, int* counters, float* loss){
  int i = blockIdx.x*blockDim.x + threadIdx.x;
  if (i < N_GR) cnt_all[i] = 0;
  if (i < DIM){ S[i] = 0.f; Se[i] = 0.f; }
  if (i < 2) counters[i] = 0;
  if (i == 0) loss[0] = 0.f;
}

// ---------------- kernel A: fused MLP -> sigmoid mask + per-graph histogram ----------------
// block = 256 threads = 4 waves; 64 rows staged in LDS (coalesced); wave q owns cols [q*128, q*128+128)
__global__ __launch_bounds__(256) void mask_gemm(
    const float* __restrict__ hsub, const float* __restrict__ W1,
    const float* __restrict__ b1, const float* __restrict__ W2,
    const float* __restrict__ b2, const int* __restrict__ s2g,
    float* __restrict__ mask_out, int* __restrict__ cnt_all)
{
  __shared__ float a_lds[64*LDS_STRIDE];   // 66,560 B
  __shared__ float sred[256];
  const int tid = threadIdx.x;
  const int r = tid & 63;
  const int q = tid >> 6;

  // ---- stage 64 rows of h_sub, fully coalesced (16B/lane, consecutive) ----
  const float* __restrict__ gbase = hsub + (size_t)blockIdx.x*64*DIM;
  #pragma unroll
  for (int i = 0; i < 16; ++i){
    const int idx = i*256 + tid;        // 0..4095 chunks of 4 floats
    const int rr = idx >> 6;            // row 0..63
    const int ch = idx & 63;            // chunk-of-4 within row
    const float4 v = *reinterpret_cast<const float4*>(gbase + (size_t)idx*4);
    *reinterpret_cast<float4*>(&a_lds[rr*LDS_STRIDE + ch*4]) = v;
  }
  __syncthreads();

  // ---- compute: each thread = one row (r), wave's 128-col slice, 4 groups of 32 ----
  float s = 0.f;
  for (int jg = 0; jg < 4; ++jg){
    const int jbase = q*128 + jg*32;
    float y[32];
    #pragma unroll
    for (int j = 0; j < 32; ++j) y[j] = b1[jbase+j];
    for (int kc = 0; kc < 16; ++kc){
      float a[16];
      #pragma unroll
      for (int kk = 0; kk < 4; ++kk){
        const float4 v = *reinterpret_cast<const float4*>(&a_lds[r*LDS_STRIDE + kc*16 + kk*4]);
        a[kk*4+0]=v.x; a[kk*4+1]=v.y; a[kk*4+2]=v.z; a[kk*4+3]=v.w;
      }
      #pragma unroll
      for (int k = 0; k < 16; ++k){
        const float4* __restrict__ wr =
            reinterpret_cast<const float4*>(W1 + (size_t)(kc*16+k)*512 + jbase);
        #pragma unroll
        for (int j4 = 0; j4 < 8; ++j4){
          const float4 w = wr[j4];
          y[j4*4+0] = fmaf(a[k], w.x, y[j4*4+0]);
          y[j4*4+1] = fmaf(a[k], w.y, y[j4*4+1]);
          y[j4*4+2] = fmaf(a[k], w.z, y[j4*4+2]);
          y[j4*4+3] = fmaf(a[k], w.w, y[j4*4+3]);
        }
      }
    }
    #pragma unroll
    for (int j = 0; j < 32; ++j) s += fmaxf(y[j], 0.f) * W2[jbase+j];
  }
  sred[tid] = s;
  __syncthreads();
  if (tid < 64){
    const float tot = sred[tid] + sred[tid+64] + sred[tid+128] + sred[tid+192] + b2[0];
    const float m = 1.f / (1.f + expf(-tot));
    const int rr = blockIdx.x*64 + tid;
    mask_out[rr] = m;
    atomicAdd(&cnt_all[s2g[rr]], 1);
  }
}

// ---------------- CSR build: scan + fill ----------------
__global__ __launch_bounds__(1024) void scan_kernel(const int* __restrict__ cnt,
                                                    int* __restrict__ offs,
                                                    int* __restrict__ cursor){
  __shared__ int buf[1024];
  const int t = threadIdx.x;
  const int c0 = cnt[t*4], c1 = cnt[t*4+1], c2 = cnt[t*4+2], c3 = cnt[t*4+3];
  const int s = c0+c1+c2+c3;
  buf[t] = s; __syncthreads();
  for (int d = 1; d < 1024; d <<= 1){
    int v = (t >= d) ? buf[t-d] : 0;
    __syncthreads();
    buf[t] += v;
    __syncthreads();
  }
  const int excl = buf[t] - s;
  const int o0 = excl, o1 = excl+c0, o2 = o1+c1, o3 = o2+c2;
  offs[t*4]=o0; offs[t*4+1]=o1; offs[t*4+2]=o2; offs[t*4+3]=o3;
  cursor[t*4]=o0; cursor[t*4+1]=o1; cursor[t*4+2]=o2; cursor[t*4+3]=o3;
  if (t == 1023) offs[4096] = buf[1023];
}

__global__ void fill_kernel(const int* __restrict__ s2g, int* __restrict__ cursor,
                            int* __restrict__ list){
  const int i = blockIdx.x*blockDim.x + threadIdx.x;
  if (i < N_SUB){
    const int g = s2g[i];
    const int p = atomicAdd(&cursor[g], 1);
    list[p] = i;
  }
}

// ---------------- kernel C: per-graph masked means + norms + nz + fused out-GEMM ----------------
__global__ __launch_bounds__(256) void graph_means(
    const float* __restrict__ hsub, const float* __restrict__ mask,
    const int* __restrict__ list, const int* __restrict__ offs,
    const float* __restrict__ hgraph, const float* __restrict__ Wc,
    const float* __restrict__ bc, float* __restrict__ hatA,
    float* __restrict__ S, float* __restrict__ Se,
    int* __restrict__ nzflags, int* __restrict__ counters,
    float* __restrict__ out)
{
  __shared__ float red[256];
  const int g = blockIdx.x;
  const int t = threadIdx.x;
  const int start = offs[g], end = offs[g+1];
  float sv = 0.f, sev = 0.f;
  int cv = 0, ce = 0;
  for (int p = start; p < end; ++p){
    const int i = list[p];
    const float m = mask[i];                 // broadcast
    const float v = hsub[(size_t)i*DIM + t]; // coalesced row
    if (m > 0.4f)      { sv  += v; cv++; }
    else if (m <= 0.3f){ sev += v; ce++; }
  }
  const float aligned = sv  / fmaxf((float)cv, 1.f);
  const float envv    = sev / fmaxf((float)ce, 1.f);
  const float an2  = block_reduce_sum_256(aligned*aligned, red);
  const float en2  = block_reduce_sum_256(envv*envv, red);
  const float nzpf = block_reduce_sum_256(aligned != 0.f ? 1.f : 0.f, red);
  const float nzef = block_reduce_sum_256(envv    != 0.f ? 1.f : 0.f, red);
  const bool nzp = nzpf > 0.f, nze = nzef > 0.f;
  const float an = fmaxf(sqrtf(an2), 1e-8f);
  const float en = fmaxf(sqrtf(en2), 1e-8f);
  const float ha = aligned / an;
  hatA[(size_t)g*DIM + t] = ha;
  atomicAdd(&S[t], ha);                 // zero rows contribute 0 anyway
  if (nze) atomicAdd(&Se[t], envv / en);
  if (t == 0){
    nzflags[g] = nzp ? 1 : 0;
    if (nzp) atomicAdd(&counters[0], 1);
    if (nze) atomicAdd(&counters[1], 1);
  }
  // fused: out[g] = concat(h_graph[g], aligned[g]) @ Wc + bc
  const float hg = hgraph[(size_t)g*DIM + t];
  #pragma unroll
  for (int c = 0; c < TCLS; ++c){
    const float part = hg*Wc[t*TCLS+c] + aligned*Wc[(DIM+t)*TCLS+c];
    const float tot = block_reduce_sum_256(part, red);
    if (t == 0) out[g*TCLS + c] = tot + bc[c];
  }
}

// ---------------- kernel D: contrastive loss via rank-1 identity ----------------
__global__ __launch_bounds__(256) void loss_kernel(
    const float* __restrict__ hatA, const float* __restrict__ S,
    const float* __restrict__ Se, const int* __restrict__ nzflags,
    const int* __restrict__ counters, float* __restrict__ loss)
{
  __shared__ float red[256];
  const int g = blockIdx.x, t = threadIdx.x;
  const float ha = hatA[(size_t)g*DIM + t];
  const float dS  = block_reduce_sum_256(ha*S[t], red);
  const float dSe = block_reduce_sum_256(ha*Se[t], red);
  if (t == 0){
    const int nzp_cnt = counters[0];
    const int nenv = counters[1];
    const float pos_num = fmaxf((float)(nzp_cnt - 1), 1.f);
    const float positive = (4096.f - dS) / pos_num;
    const float negative = ((float)nenv - dSe) / fmaxf((float)nenv, 1.f);
    float contrib = fmaxf(positive - negative + 1.f, 0.f);
    contrib *= (nzflags[g] ? 1.f : 0.f) * ((nenv > 0) ? 1.f : 0.f);
    atomicAdd(loss, contrib * (1.f/4096.f));
  }
}

// ---------------- launch ----------------
extern "C" void kernel_launch(void* const* d_in, const int* in_sizes, int n_in,
                              void* d_out, int out_size, void* d_ws, size_t ws_size,
                              hipStream_t stream) {
  const float* h_graph = (const float*)d_in[0];
  const float* h_sub   = (const float*)d_in[1];
  const float* W1      = (const float*)d_in[2];
  const float* b1      = (const float*)d_in[3];
  const float* W2      = (const float*)d_in[4];
  const float* b2      = (const float*)d_in[5];
  const float* Wc      = (const float*)d_in[6];
  const float* bc      = (const float*)d_in[7];
  const int*   s2g     = (const int*)d_in[8];

  float* out  = (float*)d_out;          // [4096,10]
  float* loss = out + N_GR*TCLS;        // scalar at 40960
  float* mask = loss + 1;               // [200000] at 40961

  // workspace layout (all 4-byte types)
  int* cnt_all  = (int*)d_ws;           // 4096
  int* offs     = cnt_all + N_GR;       // 4097
  int* cursor   = offs + N_GR + 1;      // 4096
  int* list     = cursor + N_GR;        // 200000
  int* nzflags  = list + N_SUB;         // 4096
  int* counters = nzflags + N_GR;       // 2
  float* S      = (float*)(counters + 2);  // 256
  float* Se     = S + DIM;                 // 256
  float* hatA   = Se + DIM;                // 4096*256

  hipLaunchKernelGGL(init_kernel, dim3(16), dim3(256), 0, stream,
                     cnt_all, S, Se, counters, loss);
  hipLaunchKernelGGL(mask_gemm, dim3(N_SUB/64), dim3(256), 0, stream,
                     h_sub, W1, b1, W2, b2, s2g, mask, cnt_all);
  hipLaunchKernelGGL(scan_kernel, dim3(1), dim3(1024), 0, stream,
                     cnt_all, offs, cursor);
  hipLaunchKernelGGL(fill_kernel, dim3((N_SUB+255)/256), dim3(256), 0, stream,
                     s2g, cursor, list);
  hipLaunchKernelGGL(graph_means, dim3(N_GR), dim3(256), 0, stream,
                     h_sub, mask, list, offs, h_graph, Wc, bc,
                     hatA, S, Se, nzflags, counters, out);
  hipLaunchKernelGGL(loss_kernel, dim3(N_GR), dim3(256), 0, stream,
                     hatA, S, Se, nzflags, counters, loss);
}

// Round 8
// 605.893 us; speedup vs baseline: 6.5616x; 5.8778x over previous
//
#include <hip/hip_runtime.h>

#define N_SUB 200000
#define N_GR  4096
#define DIM   256
#define HID   512
#define TCLS  10
#define KH    128            // K-half staged per phase
#define AP    136            // LDS row stride (shorts) for a K-half: 128 + 8 pad (16B aligned)
#define RCAP  16384          // borderline-refine list capacity

typedef __attribute__((ext_vector_type(8))) short short8;
typedef __attribute__((ext_vector_type(4))) float f32x4;

__device__ __forceinline__ short bf16_rne(float x){
  unsigned u = __builtin_bit_cast(unsigned, x);
  unsigned r = (u + 0x7FFFu + ((u >> 16) & 1u)) >> 16;
  return (short)r;
}
__device__ __forceinline__ float bf16_to_f(short h){
  unsigned u = ((unsigned)(unsigned short)h) << 16;
  return __builtin_bit_cast(float, u);
}

__device__ __forceinline__ float block_reduce_sum_256(float v, float* red){
  int t = threadIdx.x;
  red[t] = v; __syncthreads();
  #pragma unroll
  for (int s = 128; s > 0; s >>= 1){
    if (t < s) red[t] += red[t+s];
    __syncthreads();
  }
  float r = red[0];
  __syncthreads();
  return r;
}

// ---------------- init (graph replays -> zero every call) ----------------
__global__ void init_kernel(int* cnt_all, float* S, float* Se, int* counters,
                            float* loss, int* rcnt){
  int i = blockIdx.x*blockDim.x + threadIdx.x;
  if (i < N_GR) cnt_all[i] = 0;
  if (i < DIM){ S[i] = 0.f; Se[i] = 0.f; }
  if (i < 2) counters[i] = 0;
  if (i == 0){ loss[0] = 0.f; rcnt[0] = 0; }
}

// ---------------- W1 -> transposed bf16 hi/lo planes: Bt[n][k] ----------------
__global__ __launch_bounds__(256) void bconv_kernel(const float* __restrict__ W1,
                                                    short* __restrict__ bth,
                                                    short* __restrict__ btl){
  const int i = blockIdx.x*256 + threadIdx.x;   // 0..131071, coalesced read
  const int k = i >> 9;        // 0..255
  const int j = i & 511;       // 0..511
  const float x = W1[i];       // W1[k][j]
  const short h = bf16_rne(x);
  const short l = bf16_rne(x - bf16_to_f(h));
  bth[j*256 + k] = h;
  btl[j*256 + k] = l;
}

// ---------------- kernel A: MFMA hi/lo-split MLP -> sigmoid mask ----------------
// 512 thr = 8 waves; 64 rows/block; wave q owns cols [q*64, q*64+64) (4 n-tiles)
// K staged in two 128-halves -> LDS 36 KB -> 4 blocks/CU.
__global__ __launch_bounds__(512) void mask_gemm(
    const float* __restrict__ hsub, const short* __restrict__ bth,
    const short* __restrict__ btl, const float* __restrict__ b1,
    const float* __restrict__ W2, const float* __restrict__ b2,
    const int* __restrict__ s2g, float* __restrict__ mask_out,
    int* __restrict__ cnt_all, int* __restrict__ rlist, int* __restrict__ rcnt)
{
  __shared__ short a_hi[64*AP];     // 17408 B
  __shared__ short a_lo[64*AP];     // 17408 B
  __shared__ float sred[512];       // 2048 B
  const int tid = threadIdx.x;
  const int lane = tid & 63;
  const int q = tid >> 6;           // wave 0..7
  const int mrow = lane & 15;
  const int kgrp = lane >> 4;       // 0..3

  f32x4 acc[4][4];
  #pragma unroll
  for (int mt=0; mt<4; ++mt)
    #pragma unroll
    for (int nt=0; nt<4; ++nt) acc[mt][nt] = (f32x4){0.f,0.f,0.f,0.f};

  const float* __restrict__ gbase = hsub + (size_t)blockIdx.x*64*DIM;

  for (int ph = 0; ph < 2; ++ph){
    __syncthreads();   // previous-phase LDS reads complete before overwrite
    // ---- stage 64 rows x 128 k, coalesced 16B/lane, fp32 -> hi/lo bf16 ----
    #pragma unroll
    for (int i = 0; i < 4; ++i){
      const int idx = i*512 + tid;        // float4 chunk 0..2047
      const int rr = idx >> 5;            // row 0..63 (32 chunks/row)
      const int ch = (idx & 31)*4;        // col within half (floats)
      const float4 v = *reinterpret_cast<const float4*>(gbase + (size_t)rr*DIM + ph*KH + ch);
      const short h0=bf16_rne(v.x), h1=bf16_rne(v.y), h2=bf16_rne(v.z), h3=bf16_rne(v.w);
      const short l0=bf16_rne(v.x-bf16_to_f(h0)), l1=bf16_rne(v.y-bf16_to_f(h1));
      const short l2=bf16_rne(v.z-bf16_to_f(h2)), l3=bf16_rne(v.w-bf16_to_f(h3));
      *reinterpret_cast<short4*>(&a_hi[rr*AP + ch]) = make_short4(h0,h1,h2,h3);
      *reinterpret_cast<short4*>(&a_lo[rr*AP + ch]) = make_short4(l0,l1,l2,l3);
    }
    __syncthreads();
    // ---- 4 K-steps of 32 within this half ----
    for (int ks = 0; ks < 4; ++ks){
      short8 Ah[4], Al[4];
      #pragma unroll
      for (int mt=0; mt<4; ++mt){
        const int ao = (mt*16 + mrow)*AP + ks*32 + kgrp*8;
        Ah[mt] = *reinterpret_cast<const short8*>(&a_hi[ao]);
        Al[mt] = *reinterpret_cast<const short8*>(&a_lo[ao]);
      }
      #pragma unroll
      for (int nt=0; nt<4; ++nt){
        const size_t bo = (size_t)(q*64 + nt*16 + mrow)*256 + ph*KH + ks*32 + kgrp*8;
        const short8 Bh = *reinterpret_cast<const short8*>(bth + bo);
        const short8 Bl = *reinterpret_cast<const short8*>(btl + bo);
        #pragma unroll
        for (int mt=0; mt<4; ++mt){
          acc[mt][nt] = __builtin_amdgcn_mfma_f32_16x16x32_bf16(Ah[mt], Bh, acc[mt][nt], 0,0,0);
          acc[mt][nt] = __builtin_amdgcn_mfma_f32_16x16x32_bf16(Ah[mt], Bl, acc[mt][nt], 0,0,0);
          acc[mt][nt] = __builtin_amdgcn_mfma_f32_16x16x32_bf16(Al[mt], Bh, acc[mt][nt], 0,0,0);
        }
      }
    }
  }

  // ---- epilogue: bias + ReLU + W2 dot; reduce 16 n-lanes; combine 8 waves ----
  float w2v[4], b1v[4];
  #pragma unroll
  for (int nt=0; nt<4; ++nt){
    const int n = q*64 + nt*16 + mrow;    // C: col = lane&15
    w2v[nt] = W2[n]; b1v[nt] = b1[n];
  }
  #pragma unroll
  for (int mt=0; mt<4; ++mt){
    #pragma unroll
    for (int r=0; r<4; ++r){
      float s = 0.f;
      #pragma unroll
      for (int nt=0; nt<4; ++nt)
        s += fmaxf(acc[mt][nt][r] + b1v[nt], 0.f) * w2v[nt];
      s += __shfl_xor(s, 1, 64);
      s += __shfl_xor(s, 2, 64);
      s += __shfl_xor(s, 4, 64);
      s += __shfl_xor(s, 8, 64);
      if (mrow == 0)
        sred[q*64 + mt*16 + kgrp*4 + r] = s;   // C: row = (lane>>4)*4 + reg
    }
  }
  __syncthreads();
  if (tid < 64){
    float tot = b2[0];
    #pragma unroll
    for (int w = 0; w < 8; ++w) tot += sred[w*64 + tid];
    const float m = 1.f / (1.f + expf(-tot));
    const int rr = blockIdx.x*64 + tid;
    mask_out[rr] = m;
    atomicAdd(&cnt_all[s2g[rr]], 1);
    // borderline rows -> exact fp32 recompute (threshold semantics match fp32 ref)
    if (fabsf(m - 0.4f) < 1e-3f || fabsf(m - 0.3f) < 1e-3f){
      const int p = atomicAdd(rcnt, 1);
      if (p < RCAP) rlist[p] = rr;
    }
  }
}

// ---------------- refine: exact fp32 logit for borderline rows ----------------
__global__ __launch_bounds__(256) void refine_kernel(
    const float* __restrict__ hsub, const float* __restrict__ W1,
    const float* __restrict__ b1, const float* __restrict__ W2,
    const float* __restrict__ b2, const int* __restrict__ rlist,
    const int* __restrict__ rcnt, float* __restrict__ mask_out)
{
  __shared__ float arow[256];
  __shared__ float red[256];
  const int n = min(rcnt[0], RCAP);
  const int t = threadIdx.x;
  for (int it = blockIdx.x; it < n; it += gridDim.x){
    const int row = rlist[it];
    arow[t] = hsub[(size_t)row*DIM + t];
    __syncthreads();
    float s = 0.f;
    #pragma unroll
    for (int jj = 0; jj < 2; ++jj){
      const int j = jj*256 + t;
      float y = b1[j];
      for (int k = 0; k < 256; ++k)
        y = fmaf(arow[k], W1[(size_t)k*512 + j], y);
      s += fmaxf(y, 0.f) * W2[j];
    }
    const float tot = block_reduce_sum_256(s, red);
    if (t == 0) mask_out[row] = 1.f / (1.f + expf(-(tot + b2[0])));
    __syncthreads();
  }
}

// ---------------- CSR build: scan + fill ----------------
__global__ __launch_bounds__(1024) void scan_kernel(const int* __restrict__ cnt,
                                                    int* __restrict__ offs,
                                                    int* __restrict__ cursor){
  __shared__ int buf[1024];
  const int t = threadIdx.x;
  const int c0 = cnt[t*4], c1 = cnt[t*4+1], c2 = cnt[t*4+2], c3 = cnt[t*4+3];
  const int s = c0+c1+c2+c3;
  buf[t] = s; __syncthreads();
  for (int d = 1; d < 1024; d <<= 1){
    int v = (t >= d) ? buf[t-d] : 0;
    __syncthreads();
    buf[t] += v;
    __syncthreads();
  }
  const int excl = buf[t] - s;
  const int o0 = excl, o1 = excl+c0, o2 = o1+c1, o3 = o2+c2;
  offs[t*4]=o0; offs[t*4+1]=o1; offs[t*4+2]=o2; offs[t*4+3]=o3;
  cursor[t*4]=o0; cursor[t*4+1]=o1; cursor[t*4+2]=o2; cursor[t*4+3]=o3;
  if (t == 1023) offs[4096] = buf[1023];
}

__global__ void fill_kernel(const int* __restrict__ s2g, int* __restrict__ cursor,
                            int* __restrict__ list){
  const int i = blockIdx.x*blockDim.x + threadIdx.x;
  if (i < N_SUB){
    const int g = s2g[i];
    const int p = atomicAdd(&cursor[g], 1);
    list[p] = i;
  }
}

// ---------------- kernel C: per-graph masked means + norms + nz + fused out-GEMM ----------------
__global__ __launch_bounds__(256) void graph_means(
    const float* __restrict__ hsub, const float* __restrict__ mask,
    const int* __restrict__ list, const int* __restrict__ offs,
    const float* __restrict__ hgraph, const float* __restrict__ Wc,
    const float* __restrict__ bc, unsigned short* __restrict__ hatAb,
    float* __restrict__ S, float* __restrict__ Se,
    int* __restrict__ nzflags, int* __restrict__ counters,
    float* __restrict__ out)
{
  __shared__ float red[256];
  const int g = blockIdx.x;
  const int t = threadIdx.x;
  const int start = offs[g], end = offs[g+1];
  float sv = 0.f, sev = 0.f;
  int cv = 0, ce = 0;
  for (int p = start; p < end; ++p){
    const int i = list[p];
    const float m = mask[i];
    const float v = hsub[(size_t)i*DIM + t];
    if (m > 0.4f)      { sv  += v; cv++; }
    else if (m <= 0.3f){ sev += v; ce++; }
  }
  const float aligned = sv  / fmaxf((float)cv, 1.f);
  const float envv    = sev / fmaxf((float)ce, 1.f);
  const float an2  = block_reduce_sum_256(aligned*aligned, red);
  const float en2  = block_reduce_sum_256(envv*envv, red);
  const float nzpf = block_reduce_sum_256(aligned != 0.f ? 1.f : 0.f, red);
  const float nzef = block_reduce_sum_256(envv    != 0.f ? 1.f : 0.f, red);
  const bool nzp = nzpf > 0.f, nze = nzef > 0.f;
  const float an = fmaxf(sqrtf(an2), 1e-8f);
  const float en = fmaxf(sqrtf(en2), 1e-8f);
  const float ha = aligned / an;
  hatAb[(size_t)g*DIM + t] = (unsigned short)bf16_rne(ha);
  atomicAdd(&S[t], ha);
  if (nze) atomicAdd(&Se[t], envv / en);
  if (t == 0){
    nzflags[g] = nzp ? 1 : 0;
    if (nzp) atomicAdd(&counters[0], 1);
    if (nze) atomicAdd(&counters[1], 1);
  }
  const float hg = hgraph[(size_t)g*DIM + t];
  #pragma unroll
  for (int c = 0; c < TCLS; ++c){
    const float part = hg*Wc[t*TCLS+c] + aligned*Wc[(DIM+t)*TCLS+c];
    const float tot = block_reduce_sum_256(part, red);
    if (t == 0) out[g*TCLS + c] = tot + bc[c];
  }
}

// ---------------- kernel D: contrastive loss via rank-1 identity ----------------
__global__ __launch_bounds__(256) void loss_kernel(
    const unsigned short* __restrict__ hatAb, const float* __restrict__ S,
    const float* __restrict__ Se, const int* __restrict__ nzflags,
    const int* __restrict__ counters, float* __restrict__ loss)
{
  __shared__ float red[256];
  const int g = blockIdx.x, t = threadIdx.x;
  const float ha = bf16_to_f((short)hatAb[(size_t)g*DIM + t]);
  const float dS  = block_reduce_sum_256(ha*S[t], red);
  const float dSe = block_reduce_sum_256(ha*Se[t], red);
  if (t == 0){
    const int nzp_cnt = counters[0];
    const int nenv = counters[1];
    const float pos_num = fmaxf((float)(nzp_cnt - 1), 1.f);
    const float positive = (4096.f - dS) / pos_num;
    const float negative = ((float)nenv - dSe) / fmaxf((float)nenv, 1.f);
    float contrib = fmaxf(positive - negative + 1.f, 0.f);
    contrib *= (nzflags[g] ? 1.f : 0.f) * ((nenv > 0) ? 1.f : 0.f);
    atomicAdd(loss, contrib * (1.f/4096.f));
  }
}

// ---------------- launch ----------------
extern "C" void kernel_launch(void* const* d_in, const int* in_sizes, int n_in,
                              void* d_out, int out_size, void* d_ws, size_t ws_size,
                              hipStream_t stream) {
  const float* h_graph = (const float*)d_in[0];
  const float* h_sub   = (const float*)d_in[1];
  const float* W1      = (const float*)d_in[2];
  const float* b1      = (const float*)d_in[3];
  const float* W2      = (const float*)d_in[4];
  const float* b2      = (const float*)d_in[5];
  const float* Wc      = (const float*)d_in[6];
  const float* bc      = (const float*)d_in[7];
  const int*   s2g     = (const int*)d_in[8];

  float* out  = (float*)d_out;          // [4096,10]
  float* loss = out + N_GR*TCLS;        // scalar
  float* mask = loss + 1;               // [200000]

  // workspace layout — total ~3.5 MB (proven-safe envelope from rounds 3/6 is >=5.06 MB)
  char* ws = (char*)d_ws;
  short* bth    = (short*)ws;                          // 131072 shorts (256 KB)
  short* btl    = bth + HID*DIM;                       // 256 KB
  unsigned short* hatAb = (unsigned short*)(btl + HID*DIM);  // 4096*256 bf16 (2 MB)
  int* cnt_all  = (int*)(hatAb + (size_t)N_GR*DIM);    // 4096
  int* offs     = cnt_all + N_GR;                      // 4097
  int* cursor   = offs + N_GR + 1;                     // 4096
  int* list     = cursor + N_GR;                       // 200000
  int* nzflags  = list + N_SUB;                        // 4096
  int* counters = nzflags + N_GR;                      // 2
  int* rcnt     = counters + 2;                        // 1
  int* rlist    = rcnt + 1;                            // 16384
  float* S      = (float*)(rlist + RCAP);              // 256
  float* Se     = S + DIM;                             // 256

  hipLaunchKernelGGL(init_kernel, dim3(16), dim3(256), 0, stream,
                     cnt_all, S, Se, counters, loss, rcnt);
  hipLaunchKernelGGL(bconv_kernel, dim3(HID*DIM/256), dim3(256), 0, stream,
                     W1, bth, btl);
  hipLaunchKernelGGL(mask_gemm, dim3(N_SUB/64), dim3(512), 0, stream,
                     h_sub, bth, btl, b1, W2, b2, s2g, mask, cnt_all, rlist, rcnt);
  hipLaunchKernelGGL(refine_kernel, dim3(256), dim3(256), 0, stream,
                     h_sub, W1, b1, W2, b2, rlist, rcnt, mask);
  hipLaunchKernelGGL(scan_kernel, dim3(1), dim3(1024), 0, stream,
                     cnt_all, offs, cursor);
  hipLaunchKernelGGL(fill_kernel, dim3((N_SUB+255)/256), dim3(256), 0, stream,
                     s2g, cursor, list);
  hipLaunchKernelGGL(graph_means, dim3(N_GR), dim3(256), 0, stream,
                     h_sub, mask, list, offs, h_graph, Wc, bc,
                     hatAb, S, Se, nzflags, counters, out);
  hipLaunchKernelGGL(loss_kernel, dim3(N_GR), dim3(256), 0, stream,
                     hatAb, S, Se, nzflags, counters, loss);
}

// Round 10
// 520.711 us; speedup vs baseline: 7.6350x; 1.1636x over previous
//
#include <hip/hip_runtime.h>

#define N_SUB 200000
#define N_GR  4096
#define DIM   256
#define HID   512
#define TCLS  10
#define KH    128            // K-half staged per phase
#define RCAP  16384          // borderline-refine list capacity
#define RMARG 1e-3f          // refine margin (3-term split: proven in round 8)

typedef __attribute__((ext_vector_type(8))) short short8;
typedef __attribute__((ext_vector_type(4))) float f32x4;

__device__ __forceinline__ short bf16_rne(float x){
  unsigned u = __builtin_bit_cast(unsigned, x);
  unsigned r = (u + 0x7FFFu + ((u >> 16) & 1u)) >> 16;
  return (short)r;
}
__device__ __forceinline__ float bf16_to_f(short h){
  unsigned u = ((unsigned)(unsigned short)h) << 16;
  return __builtin_bit_cast(float, u);
}
__device__ __forceinline__ float wave_reduce(float v){
  #pragma unroll
  for (int d = 1; d < 64; d <<= 1) v += __shfl_xor(v, d, 64);
  return v;
}
// swizzled fragment-major A granule index (16B granules); used by BOTH writer & reader
__device__ __forceinline__ int a_gran(int mt, int mrow, int ks, int kgrp){
  return (((((mt*4 + ks)*4 + kgrp)*2 + (mrow>>3)) << 3)
          | ((mrow & 7) ^ (ks << 1) ^ (kgrp & 1)));
}

__device__ __forceinline__ float block_reduce_sum_256(float v, float* red){
  int t = threadIdx.x;
  red[t] = v; __syncthreads();
  #pragma unroll
  for (int s = 128; s > 0; s >>= 1){
    if (t < s) red[t] += red[t+s];
    __syncthreads();
  }
  float r = red[0];
  __syncthreads();
  return r;
}

// ---------------- init (graph replays -> zero every call) ----------------
__global__ void init_kernel(int* cnt_all, float* S, float* Se, int* counters,
                            float* loss, int* rcnt){
  int i = blockIdx.x*blockDim.x + threadIdx.x;
  if (i < N_GR) cnt_all[i] = 0;
  if (i < DIM){ S[i] = 0.f; Se[i] = 0.f; }
  if (i < 2) counters[i] = 0;
  if (i == 0){ loss[0] = 0.f; rcnt[0] = 0; }
}

// ---------------- W1 -> fragment-major packed bf16 hi/lo ----------------
// dst: [nt 0..31][ksg 0..7][lane 0..63][kk 0..7]; lane = kgrp*16 + mrow
__global__ __launch_bounds__(256) void bconv_kernel(const float* __restrict__ W1,
                                                    short* __restrict__ bth,
                                                    short* __restrict__ btl){
  const int i = blockIdx.x*256 + threadIdx.x;   // coalesced read
  const int k = i >> 9;        // 0..255
  const int j = i & 511;       // 0..511
  const float x = W1[i];       // W1[k][j]
  const short h = bf16_rne(x);
  const short l = bf16_rne(x - bf16_to_f(h));
  const int nt = j >> 4, mrow = j & 15;
  const int ksg = k >> 5, kgrp = (k >> 3) & 3, kk = k & 7;
  const int lane = kgrp*16 + mrow;
  const size_t dst = (((size_t)(nt*8 + ksg)*64 + lane) << 3) + kk;
  bth[dst] = h;
  btl[dst] = l;
}

// ---------------- kernel A: MFMA 3-term split MLP -> sigmoid mask ----------------
// 512 thr = 8 waves; 64 rows/block; wave q owns cols [q*64, q*64+64).
// A = Ah+Al (bf16 hi/lo), B = Bh+Bl; compute AhBh + AhBl + AlBh (drop AlBl: err ~1e-6)
__global__ __launch_bounds__(512) void mask_gemm(
    const float* __restrict__ hsub, const short* __restrict__ bth,
    const short* __restrict__ btl, const float* __restrict__ b1,
    const float* __restrict__ W2, const float* __restrict__ b2,
    const int* __restrict__ s2g, float* __restrict__ mask_out,
    int* __restrict__ cnt_all, int* __restrict__ rlist, int* __restrict__ rcnt)
{
  __shared__ short a_hi[8192];      // 16 KB, swizzled fragment-major
  __shared__ short a_lo[8192];      // 16 KB
  __shared__ float sred[512];       // 2 KB
  const int tid = threadIdx.x;
  const int lane = tid & 63;
  const int q = tid >> 6;           // wave 0..7
  const int mrow = lane & 15;
  const int kgrp = lane >> 4;       // 0..3

  f32x4 acc[4][4];
  #pragma unroll
  for (int mt=0; mt<4; ++mt)
    #pragma unroll
    for (int nt=0; nt<4; ++nt) acc[mt][nt] = (f32x4){0.f,0.f,0.f,0.f};

  const float* __restrict__ gbase = hsub + (size_t)blockIdx.x*64*DIM;

  for (int ph = 0; ph < 2; ++ph){
    __syncthreads();   // prior-phase LDS reads complete before overwrite
    // ---- stage 64 rows x 128 k, coalesced 16B/lane, fp32 -> hi/lo bf16 ----
    #pragma unroll
    for (int i = 0; i < 4; ++i){
      const int idx = i*512 + tid;        // float4 chunk 0..2047
      const int rr = idx >> 5;            // row 0..63
      const int ch = idx & 31;            // float4-chunk within K-half
      const float4 v = *reinterpret_cast<const float4*>(gbase + (size_t)rr*DIM + ph*KH + ch*4);
      const short h0=bf16_rne(v.x), h1=bf16_rne(v.y), h2=bf16_rne(v.z), h3=bf16_rne(v.w);
      const short l0=bf16_rne(v.x-bf16_to_f(h0)), l1=bf16_rne(v.y-bf16_to_f(h1));
      const short l2=bf16_rne(v.z-bf16_to_f(h2)), l3=bf16_rne(v.w-bf16_to_f(h3));
      const int so = a_gran(rr>>4, rr&15, ch>>3, (ch>>1)&3)*8 + (ch&1)*4;
      *reinterpret_cast<short4*>(&a_hi[so]) = make_short4(h0,h1,h2,h3);
      *reinterpret_cast<short4*>(&a_lo[so]) = make_short4(l0,l1,l2,l3);
    }
    __syncthreads();
    // ---- 4 K-steps of 32 within this half ----
    for (int ks = 0; ks < 4; ++ks){
      short8 Ah[4], Al[4];
      #pragma unroll
      for (int mt=0; mt<4; ++mt){
        const int so = a_gran(mt, mrow, ks, kgrp)*8;
        Ah[mt] = *reinterpret_cast<const short8*>(&a_hi[so]);
        Al[mt] = *reinterpret_cast<const short8*>(&a_lo[so]);
      }
      #pragma unroll
      for (int nt=0; nt<4; ++nt){
        // packed fragment-major: wave reads 64x16B contiguous
        const size_t bo = (((size_t)((q*4 + nt)*8 + (ph*4 + ks))*64 + lane) << 3);
        const short8 Bh = *reinterpret_cast<const short8*>(bth + bo);
        const short8 Bl = *reinterpret_cast<const short8*>(btl + bo);
        #pragma unroll
        for (int mt=0; mt<4; ++mt){
          acc[mt][nt] = __builtin_amdgcn_mfma_f32_16x16x32_bf16(Ah[mt], Bh, acc[mt][nt], 0,0,0);
          acc[mt][nt] = __builtin_amdgcn_mfma_f32_16x16x32_bf16(Ah[mt], Bl, acc[mt][nt], 0,0,0);
          acc[mt][nt] = __builtin_amdgcn_mfma_f32_16x16x32_bf16(Al[mt], Bh, acc[mt][nt], 0,0,0);
        }
      }
    }
  }

  // ---- epilogue: bias + ReLU + W2 dot; reduce 16 n-lanes; combine 8 waves ----
  float w2v[4], b1v[4];
  #pragma unroll
  for (int nt=0; nt<4; ++nt){
    const int n = q*64 + nt*16 + mrow;    // C: col = lane&15
    w2v[nt] = W2[n]; b1v[nt] = b1[n];
  }
  #pragma unroll
  for (int mt=0; mt<4; ++mt){
    #pragma unroll
    for (int r=0; r<4; ++r){
      float s = 0.f;
      #pragma unroll
      for (int nt=0; nt<4; ++nt)
        s += fmaxf(acc[mt][nt][r] + b1v[nt], 0.f) * w2v[nt];
      s += __shfl_xor(s, 1, 64);
      s += __shfl_xor(s, 2, 64);
      s += __shfl_xor(s, 4, 64);
      s += __shfl_xor(s, 8, 64);
      if (mrow == 0)
        sred[q*64 + mt*16 + kgrp*4 + r] = s;   // C: row = (lane>>4)*4 + reg
    }
  }
  __syncthreads();
  if (tid < 64){
    float tot = b2[0];
    #pragma unroll
    for (int w = 0; w < 8; ++w) tot += sred[w*64 + tid];
    const float m = 1.f / (1.f + expf(-tot));
    const int rr = blockIdx.x*64 + tid;
    mask_out[rr] = m;
    atomicAdd(&cnt_all[s2g[rr]], 1);
    // borderline rows -> exact fp32 recompute
    if (fabsf(m - 0.4f) < RMARG || fabsf(m - 0.3f) < RMARG){
      const int p = atomicAdd(rcnt, 1);
      if (p < RCAP) rlist[p] = rr;
    }
  }
}

// ---------------- refine: exact fp32 logit for borderline rows ----------------
__global__ __launch_bounds__(256) void refine_kernel(
    const float* __restrict__ hsub, const float* __restrict__ W1,
    const float* __restrict__ b1, const float* __restrict__ W2,
    const float* __restrict__ b2, const int* __restrict__ rlist,
    const int* __restrict__ rcnt, float* __restrict__ mask_out)
{
  __shared__ float arow[256];
  __shared__ float red[256];
  const int n = min(rcnt[0], RCAP);
  const int t = threadIdx.x;
  for (int it = blockIdx.x; it < n; it += gridDim.x){
    const int row = rlist[it];
    arow[t] = hsub[(size_t)row*DIM + t];
    __syncthreads();
    float s = 0.f;
    #pragma unroll
    for (int jj = 0; jj < 2; ++jj){
      const int j = jj*256 + t;
      float y = b1[j];
      for (int k = 0; k < 256; ++k)
        y = fmaf(arow[k], W1[(size_t)k*512 + j], y);
      s += fmaxf(y, 0.f) * W2[j];
    }
    const float tot = block_reduce_sum_256(s, red);
    if (t == 0) mask_out[row] = 1.f / (1.f + expf(-(tot + b2[0])));
    __syncthreads();
  }
}

// ---------------- CSR build: scan + fill ----------------
__global__ __launch_bounds__(1024) void scan_kernel(const int* __restrict__ cnt,
                                                    int* __restrict__ offs,
                                                    int* __restrict__ cursor){
  __shared__ int buf[1024];
  const int t = threadIdx.x;
  const int c0 = cnt[t*4], c1 = cnt[t*4+1], c2 = cnt[t*4+2], c3 = cnt[t*4+3];
  const int s = c0+c1+c2+c3;
  buf[t] = s; __syncthreads();
  for (int d = 1; d < 1024; d <<= 1){
    int v = (t >= d) ? buf[t-d] : 0;
    __syncthreads();
    buf[t] += v;
    __syncthreads();
  }
  const int excl = buf[t] - s;
  const int o0 = excl, o1 = excl+c0, o2 = o1+c1, o3 = o2+c2;
  offs[t*4]=o0; offs[t*4+1]=o1; offs[t*4+2]=o2; offs[t*4+3]=o3;
  cursor[t*4]=o0; cursor[t*4+1]=o1; cursor[t*4+2]=o2; cursor[t*4+3]=o3;
  if (t == 1023) offs[4096] = buf[1023];
}

__global__ void fill_kernel(const int* __restrict__ s2g, int* __restrict__ cursor,
                            int* __restrict__ list){
  const int i = blockIdx.x*blockDim.x + threadIdx.x;
  if (i < N_SUB){
    const int g = s2g[i];
    const int p = atomicAdd(&cursor[g], 1);
    list[p] = i;
  }
}

// ---------------- kernel C: per-graph masked means + norms + nz + fused out-GEMM ----------------
__global__ __launch_bounds__(256) void graph_means(
    const float* __restrict__ hsub, const float* __restrict__ mask,
    const int* __restrict__ list, const int* __restrict__ offs,
    const float* __restrict__ hgraph, const float* __restrict__ Wc,
    const float* __restrict__ bc, unsigned short* __restrict__ hatAb,
    float* __restrict__ S, float* __restrict__ Se,
    int* __restrict__ nzflags, int* __restrict__ counters,
    float* __restrict__ out)
{
  __shared__ float wr4[4][4];
  __shared__ float wrc[TCLS][4];
  const int g = blockIdx.x;
  const int t = threadIdx.x;
  const int w = t >> 6, lane = t & 63;
  const int start = offs[g], end = offs[g+1];
  float sv = 0.f, sev = 0.f;
  int cv = 0, ce = 0;
  for (int p = start; p < end; ++p){
    const int i = list[p];
    const float m = mask[i];
    const float v = hsub[(size_t)i*DIM + t];
    if (m > 0.4f)      { sv  += v; cv++; }
    else if (m <= 0.3f){ sev += v; ce++; }
  }
  const float aligned = sv  / fmaxf((float)cv, 1.f);
  const float envv    = sev / fmaxf((float)ce, 1.f);
  float r0 = wave_reduce(aligned*aligned);
  float r1 = wave_reduce(envv*envv);
  float r2 = wave_reduce(aligned != 0.f ? 1.f : 0.f);
  float r3 = wave_reduce(envv    != 0.f ? 1.f : 0.f);
  if (lane == 0){ wr4[w][0]=r0; wr4[w][1]=r1; wr4[w][2]=r2; wr4[w][3]=r3; }
  __syncthreads();
  const float an2  = wr4[0][0]+wr4[1][0]+wr4[2][0]+wr4[3][0];
  const float en2  = wr4[0][1]+wr4[1][1]+wr4[2][1]+wr4[3][1];
  const float nzpf = wr4[0][2]+wr4[1][2]+wr4[2][2]+wr4[3][2];
  const float nzef = wr4[0][3]+wr4[1][3]+wr4[2][3]+wr4[3][3];
  const bool nzp = nzpf > 0.f, nze = nzef > 0.f;
  const float an = fmaxf(sqrtf(an2), 1e-8f);
  const float en = fmaxf(sqrtf(en2), 1e-8f);
  const float ha = aligned / an;
  hatAb[(size_t)g*DIM + t] = (unsigned short)bf16_rne(ha);
  atomicAdd(&S[t], ha);
  if (nze) atomicAdd(&Se[t], envv / en);
  if (t == 0){
    nzflags[g] = nzp ? 1 : 0;
    if (nzp) atomicAdd(&counters[0], 1);
    if (nze) atomicAdd(&counters[1], 1);
  }
  const float hg = hgraph[(size_t)g*DIM + t];
  #pragma unroll
  for (int c = 0; c < TCLS; ++c){
    float part = hg*Wc[t*TCLS+c] + aligned*Wc[(DIM+t)*TCLS+c];
    part = wave_reduce(part);
    if (lane == 0) wrc[c][w] = part;
  }
  __syncthreads();
  if (t < TCLS)
    out[g*TCLS + t] = wrc[t][0]+wrc[t][1]+wrc[t][2]+wrc[t][3] + bc[t];
}

// ---------------- kernel D: contrastive loss via rank-1 identity ----------------
__global__ __launch_bounds__(256) void loss_kernel(
    const unsigned short* __restrict__ hatAb, const float* __restrict__ S,
    const float* __restrict__ Se, const int* __restrict__ nzflags,
    const int* __restrict__ counters, float* __restrict__ loss)
{
  __shared__ float wr[4][2];
  const int g = blockIdx.x, t = threadIdx.x;
  const int w = t >> 6, lane = t & 63;
  const float ha = bf16_to_f((short)hatAb[(size_t)g*DIM + t]);
  float p0 = wave_reduce(ha*S[t]);
  float p1 = wave_reduce(ha*Se[t]);
  if (lane == 0){ wr[w][0] = p0; wr[w][1] = p1; }
  __syncthreads();
  if (t == 0){
    const float dS  = wr[0][0]+wr[1][0]+wr[2][0]+wr[3][0];
    const float dSe = wr[0][1]+wr[1][1]+wr[2][1]+wr[3][1];
    const int nzp_cnt = counters[0];
    const int nenv = counters[1];
    const float pos_num = fmaxf((float)(nzp_cnt - 1), 1.f);
    const float positive = (4096.f - dS) / pos_num;
    const float negative = ((float)nenv - dSe) / fmaxf((float)nenv, 1.f);
    float contrib = fmaxf(positive - negative + 1.f, 0.f);
    contrib *= (nzflags[g] ? 1.f : 0.f) * ((nenv > 0) ? 1.f : 0.f);
    atomicAdd(loss, contrib * (1.f/4096.f));
  }
}

// ---------------- launch ----------------
extern "C" void kernel_launch(void* const* d_in, const int* in_sizes, int n_in,
                              void* d_out, int out_size, void* d_ws, size_t ws_size,
                              hipStream_t stream) {
  const float* h_graph = (const float*)d_in[0];
  const float* h_sub   = (const float*)d_in[1];
  const float* W1      = (const float*)d_in[2];
  const float* b1      = (const float*)d_in[3];
  const float* W2      = (const float*)d_in[4];
  const float* b2      = (const float*)d_in[5];
  const float* Wc      = (const float*)d_in[6];
  const float* bc      = (const float*)d_in[7];
  const int*   s2g     = (const int*)d_in[8];

  float* out  = (float*)d_out;          // [4096,10]
  float* loss = out + N_GR*TCLS;        // scalar
  float* mask = loss + 1;               // [200000]

  // workspace layout — ~3.5 MB (proven-safe in round 8)
  char* ws = (char*)d_ws;
  short* bth    = (short*)ws;                          // 256 KB
  short* btl    = bth + HID*DIM;                       // 256 KB
  unsigned short* hatAb = (unsigned short*)(btl + HID*DIM);  // 2 MB
  int* cnt_all  = (int*)(hatAb + (size_t)N_GR*DIM);    // 4096
  int* offs     = cnt_all + N_GR;                      // 4097
  int* cursor   = offs + N_GR + 1;                     // 4096
  int* list     = cursor + N_GR;                       // 200000
  int* nzflags  = list + N_SUB;                        // 4096
  int* counters = nzflags + N_GR;                      // 2
  int* rcnt     = counters + 2;                        // 1
  int* rlist    = rcnt + 1;                            // 16384
  float* S      = (float*)(rlist + RCAP);              // 256
  float* Se     = S + DIM;                             // 256

  hipLaunchKernelGGL(init_kernel, dim3(16), dim3(256), 0, stream,
                     cnt_all, S, Se, counters, loss, rcnt);
  hipLaunchKernelGGL(bconv_kernel, dim3(HID*DIM/256), dim3(256), 0, stream,
                     W1, bth, btl);
  hipLaunchKernelGGL(mask_gemm, dim3(N_SUB/64), dim3(512), 0, stream,
                     h_sub, bth, btl, b1, W2, b2, s2g, mask, cnt_all, rlist, rcnt);
  hipLaunchKernelGGL(refine_kernel, dim3(384), dim3(256), 0, stream,
                     h_sub, W1, b1, W2, b2, rlist, rcnt, mask);
  hipLaunchKernelGGL(scan_kernel, dim3(1), dim3(1024), 0, stream,
                     cnt_all, offs, cursor);
  hipLaunchKernelGGL(fill_kernel, dim3((N_SUB+255)/256), dim3(256), 0, stream,
                     s2g, cursor, list);
  hipLaunchKernelGGL(graph_means, dim3(N_GR), dim3(256), 0, stream,
                     h_sub, mask, list, offs, h_graph, Wc, bc,
                     hatAb, S, Se, nzflags, counters, out);
  hipLaunchKernelGGL(loss_kernel, dim3(N_GR), dim3(256), 0, stream,
                     hatAb, S, Se, nzflags, counters, loss);
}

// Round 11
// 495.295 us; speedup vs baseline: 8.0268x; 1.0513x over previous
//
#include <hip/hip_runtime.h>

#define N_SUB 200000
#define N_GR  4096
#define DIM   256
#define HID   512
#define TCLS  10
#define KH    128            // K-half staged per phase
#define RCAP  16384          // borderline-refine list capacity
#define RMARG 1e-3f          // refine margin (3-term split: proven)

typedef __attribute__((ext_vector_type(8))) short short8;
typedef __attribute__((ext_vector_type(4))) float f32x4;

__device__ __forceinline__ short bf16_rne(float x){
  unsigned u = __builtin_bit_cast(unsigned, x);
  unsigned r = (u + 0x7FFFu + ((u >> 16) & 1u)) >> 16;
  return (short)r;
}
__device__ __forceinline__ float bf16_to_f(short h){
  unsigned u = ((unsigned)(unsigned short)h) << 16;
  return __builtin_bit_cast(float, u);
}
__device__ __forceinline__ float wave_reduce(float v){
  #pragma unroll
  for (int d = 1; d < 64; d <<= 1) v += __shfl_xor(v, d, 64);
  return v;
}
// swizzled fragment-major A granule index (16B granules); writer & reader share it
__device__ __forceinline__ int a_gran(int mt, int mrow, int ks, int kgrp){
  return (((((mt*4 + ks)*4 + kgrp)*2 + (mrow>>3)) << 3)
          | ((mrow & 7) ^ (ks << 1) ^ (kgrp & 1)));
}

__device__ __forceinline__ float block_reduce_sum_256(float v, float* red){
  int t = threadIdx.x;
  red[t] = v; __syncthreads();
  #pragma unroll
  for (int s = 128; s > 0; s >>= 1){
    if (t < s) red[t] += red[t+s];
    __syncthreads();
  }
  float r = red[0];
  __syncthreads();
  return r;
}

// ---------------- init (graph replays -> zero every call) ----------------
__global__ void init_kernel(int* cnt_all, float* S, float* Se, int* counters,
                            float* loss, int* rcnt){
  int i = blockIdx.x*blockDim.x + threadIdx.x;
  if (i < N_GR) cnt_all[i] = 0;
  if (i < DIM){ S[i] = 0.f; Se[i] = 0.f; }
  if (i < 2) counters[i] = 0;
  if (i == 0){ loss[0] = 0.f; rcnt[0] = 0; }
}

// ---------------- W1 -> fragment-major packed bf16 hi/lo ----------------
// dst: [nt 0..31][ksg 0..7][lane 0..63][kk 0..7]; lane = kgrp*16 + mrow
__global__ __launch_bounds__(256) void bconv_kernel(const float* __restrict__ W1,
                                                    short* __restrict__ bth,
                                                    short* __restrict__ btl){
  const int i = blockIdx.x*256 + threadIdx.x;   // coalesced read
  const int k = i >> 9;        // 0..255
  const int j = i & 511;       // 0..511
  const float x = W1[i];       // W1[k][j]
  const short h = bf16_rne(x);
  const short l = bf16_rne(x - bf16_to_f(h));
  const int nt = j >> 4, mrow = j & 15;
  const int ksg = k >> 5, kgrp = (k >> 3) & 3, kk = k & 7;
  const int lane = kgrp*16 + mrow;
  const size_t dst = (((size_t)(nt*8 + ksg)*64 + lane) << 3) + kk;
  bth[dst] = h;
  btl[dst] = l;
}

// ---------------- kernel A: MFMA 3-term split MLP -> sigmoid mask ----------------
// 512 thr = 8 waves; 64 rows/block; wave q owns cols [q*64, q*64+64).
// Register double-buffered B prefetch; phase-1 A loads issued at kernel start.
__global__ __launch_bounds__(512) void mask_gemm(
    const float* __restrict__ hsub, const short* __restrict__ bth,
    const short* __restrict__ btl, const float* __restrict__ b1,
    const float* __restrict__ W2, const float* __restrict__ b2,
    const int* __restrict__ s2g, float* __restrict__ mask_out,
    int* __restrict__ cnt_all, int* __restrict__ rlist, int* __restrict__ rcnt)
{
  __shared__ short a_hi[8192];      // 16 KB, swizzled fragment-major
  __shared__ short a_lo[8192];      // 16 KB
  __shared__ float sred[512];       // 2 KB
  const int tid = threadIdx.x;
  const int lane = tid & 63;
  const int q = tid >> 6;           // wave 0..7
  const int mrow = lane & 15;
  const int kgrp = lane >> 4;       // 0..3

  const float* __restrict__ gbase = hsub + (size_t)blockIdx.x*64*DIM;

  // ---- issue ALL A loads up front (ph0 + ph1); convert ph0; barrier ----
  float4 s0[4], s1[4];
  #pragma unroll
  for (int i = 0; i < 4; ++i){
    const int idx = i*512 + tid;
    s0[i] = *reinterpret_cast<const float4*>(gbase + (size_t)(idx>>5)*DIM + (idx&31)*4);
  }
  #pragma unroll
  for (int i = 0; i < 4; ++i){
    const int idx = i*512 + tid;
    s1[i] = *reinterpret_cast<const float4*>(gbase + (size_t)(idx>>5)*DIM + KH + (idx&31)*4);
  }
  #pragma unroll
  for (int i = 0; i < 4; ++i){
    const int idx = i*512 + tid;
    const int rr = idx >> 5, ch = idx & 31;
    const float4 v = s0[i];
    const short h0=bf16_rne(v.x), h1=bf16_rne(v.y), h2=bf16_rne(v.z), h3=bf16_rne(v.w);
    const short l0=bf16_rne(v.x-bf16_to_f(h0)), l1=bf16_rne(v.y-bf16_to_f(h1));
    const short l2=bf16_rne(v.z-bf16_to_f(h2)), l3=bf16_rne(v.w-bf16_to_f(h3));
    const int so = a_gran(rr>>4, rr&15, ch>>3, (ch>>1)&3)*8 + (ch&1)*4;
    *reinterpret_cast<short4*>(&a_hi[so]) = make_short4(h0,h1,h2,h3);
    *reinterpret_cast<short4*>(&a_lo[so]) = make_short4(l0,l1,l2,l3);
  }
  __syncthreads();

  f32x4 acc[4][4];
  #pragma unroll
  for (int mt=0; mt<4; ++mt)
    #pragma unroll
    for (int nt=0; nt<4; ++nt) acc[mt][nt] = (f32x4){0.f,0.f,0.f,0.f};

#define LOADB(KSG, BH, BL)                                                   \
  { _Pragma("unroll")                                                        \
    for (int nt=0; nt<4; ++nt){                                              \
      const size_t bo = (((size_t)((q*4+nt)*8 + (KSG))*64 + lane) << 3);     \
      BH[nt] = *reinterpret_cast<const short8*>(bth + bo);                   \
      BL[nt] = *reinterpret_cast<const short8*>(btl + bo);                   \
    } }

#define LOADA(KS, AH, AL)                                                    \
  { _Pragma("unroll")                                                        \
    for (int mt=0; mt<4; ++mt){                                              \
      const int so = a_gran(mt, mrow, (KS), kgrp)*8;                         \
      AH[mt] = *reinterpret_cast<const short8*>(&a_hi[so]);                  \
      AL[mt] = *reinterpret_cast<const short8*>(&a_lo[so]);                  \
    } }

#define MFMA3(AH, AL, BH, BL)                                                \
  { _Pragma("unroll")                                                        \
    for (int nt=0; nt<4; ++nt){                                              \
      _Pragma("unroll")                                                      \
      for (int mt=0; mt<4; ++mt){                                            \
        acc[mt][nt] = __builtin_amdgcn_mfma_f32_16x16x32_bf16(AH[mt], BH[nt], acc[mt][nt], 0,0,0); \
        acc[mt][nt] = __builtin_amdgcn_mfma_f32_16x16x32_bf16(AH[mt], BL[nt], acc[mt][nt], 0,0,0); \
        acc[mt][nt] = __builtin_amdgcn_mfma_f32_16x16x32_bf16(AL[mt], BH[nt], acc[mt][nt], 0,0,0); \
      } } }

  short8 BhA[4], BlA[4], BhB[4], BlB[4], Ah[4], Al[4];
  LOADB(0, BhA, BlA);
  // ---- phase 0 ----
  LOADA(0, Ah, Al); LOADB(1, BhB, BlB); MFMA3(Ah, Al, BhA, BlA);
  LOADA(1, Ah, Al); LOADB(2, BhA, BlA); MFMA3(Ah, Al, BhB, BlB);
  LOADA(2, Ah, Al); LOADB(3, BhB, BlB); MFMA3(Ah, Al, BhA, BlA);
  LOADA(3, Ah, Al); LOADB(4, BhA, BlA); MFMA3(Ah, Al, BhB, BlB);
  // ---- phase switch: write ph1 A (loaded at kernel start) ----
  __syncthreads();
  #pragma unroll
  for (int i = 0; i < 4; ++i){
    const int idx = i*512 + tid;
    const int rr = idx >> 5, ch = idx & 31;
    const float4 v = s1[i];
    const short h0=bf16_rne(v.x), h1=bf16_rne(v.y), h2=bf16_rne(v.z), h3=bf16_rne(v.w);
    const short l0=bf16_rne(v.x-bf16_to_f(h0)), l1=bf16_rne(v.y-bf16_to_f(h1));
    const short l2=bf16_rne(v.z-bf16_to_f(h2)), l3=bf16_rne(v.w-bf16_to_f(h3));
    const int so = a_gran(rr>>4, rr&15, ch>>3, (ch>>1)&3)*8 + (ch&1)*4;
    *reinterpret_cast<short4*>(&a_hi[so]) = make_short4(h0,h1,h2,h3);
    *reinterpret_cast<short4*>(&a_lo[so]) = make_short4(l0,l1,l2,l3);
  }
  __syncthreads();
  // ---- phase 1 ----
  LOADA(0, Ah, Al); LOADB(5, BhB, BlB); MFMA3(Ah, Al, BhA, BlA);
  LOADA(1, Ah, Al); LOADB(6, BhA, BlA); MFMA3(Ah, Al, BhB, BlB);
  LOADA(2, Ah, Al); LOADB(7, BhB, BlB); MFMA3(Ah, Al, BhA, BlA);
  LOADA(3, Ah, Al);                     MFMA3(Ah, Al, BhB, BlB);

  // ---- epilogue: bias + ReLU + W2 dot; reduce 16 n-lanes; combine 8 waves ----
  float w2v[4], b1v[4];
  #pragma unroll
  for (int nt=0; nt<4; ++nt){
    const int n = q*64 + nt*16 + mrow;    // C: col = lane&15
    w2v[nt] = W2[n]; b1v[nt] = b1[n];
  }
  #pragma unroll
  for (int mt=0; mt<4; ++mt){
    #pragma unroll
    for (int r=0; r<4; ++r){
      float s = 0.f;
      #pragma unroll
      for (int nt=0; nt<4; ++nt)
        s += fmaxf(acc[mt][nt][r] + b1v[nt], 0.f) * w2v[nt];
      s += __shfl_xor(s, 1, 64);
      s += __shfl_xor(s, 2, 64);
      s += __shfl_xor(s, 4, 64);
      s += __shfl_xor(s, 8, 64);
      if (mrow == 0)
        sred[q*64 + mt*16 + kgrp*4 + r] = s;   // C: row = (lane>>4)*4 + reg
    }
  }
  __syncthreads();
  if (tid < 64){
    float tot = b2[0];
    #pragma unroll
    for (int w = 0; w < 8; ++w) tot += sred[w*64 + tid];
    const float m = 1.f / (1.f + expf(-tot));
    const int rr = blockIdx.x*64 + tid;
    mask_out[rr] = m;
    atomicAdd(&cnt_all[s2g[rr]], 1);
    if (fabsf(m - 0.4f) < RMARG || fabsf(m - 0.3f) < RMARG){
      const int p = atomicAdd(rcnt, 1);
      if (p < RCAP) rlist[p] = rr;
    }
  }
#undef LOADB
#undef LOADA
#undef MFMA3
}

// ---------------- refine: exact fp32 logit for borderline rows ----------------
__global__ __launch_bounds__(256) void refine_kernel(
    const float* __restrict__ hsub, const float* __restrict__ W1,
    const float* __restrict__ b1, const float* __restrict__ W2,
    const float* __restrict__ b2, const int* __restrict__ rlist,
    const int* __restrict__ rcnt, float* __restrict__ mask_out)
{
  __shared__ float arow[256];
  __shared__ float red[256];
  const int n = min(rcnt[0], RCAP);
  const int t = threadIdx.x;
  for (int it = blockIdx.x; it < n; it += gridDim.x){
    const int row = rlist[it];
    arow[t] = hsub[(size_t)row*DIM + t];
    __syncthreads();
    float s = 0.f;
    #pragma unroll
    for (int jj = 0; jj < 2; ++jj){
      const int j = jj*256 + t;
      float y = b1[j];
      for (int k = 0; k < 256; ++k)
        y = fmaf(arow[k], W1[(size_t)k*512 + j], y);
      s += fmaxf(y, 0.f) * W2[j];
    }
    const float tot = block_reduce_sum_256(s, red);
    if (t == 0) mask_out[row] = 1.f / (1.f + expf(-(tot + b2[0])));
    __syncthreads();
  }
}

// ---------------- CSR build: scan + fill ----------------
__global__ __launch_bounds__(1024) void scan_kernel(const int* __restrict__ cnt,
                                                    int* __restrict__ offs,
                                                    int* __restrict__ cursor){
  __shared__ int buf[1024];
  const int t = threadIdx.x;
  const int c0 = cnt[t*4], c1 = cnt[t*4+1], c2 = cnt[t*4+2], c3 = cnt[t*4+3];
  const int s = c0+c1+c2+c3;
  buf[t] = s; __syncthreads();
  for (int d = 1; d < 1024; d <<= 1){
    int v = (t >= d) ? buf[t-d] : 0;
    __syncthreads();
    buf[t] += v;
    __syncthreads();
  }
  const int excl = buf[t] - s;
  const int o0 = excl, o1 = excl+c0, o2 = o1+c1, o3 = o2+c2;
  offs[t*4]=o0; offs[t*4+1]=o1; offs[t*4+2]=o2; offs[t*4+3]=o3;
  cursor[t*4]=o0; cursor[t*4+1]=o1; cursor[t*4+2]=o2; cursor[t*4+3]=o3;
  if (t == 1023) offs[4096] = buf[1023];
}

__global__ void fill_kernel(const int* __restrict__ s2g, int* __restrict__ cursor,
                            int* __restrict__ list){
  const int i = blockIdx.x*blockDim.x + threadIdx.x;
  if (i < N_SUB){
    const int g = s2g[i];
    const int p = atomicAdd(&cursor[g], 1);
    list[p] = i;
  }
}

// ---------------- kernel C: per-graph masked means (batched gather) ----------------
__global__ __launch_bounds__(256) void graph_means(
    const float* __restrict__ hsub, const float* __restrict__ mask,
    const int* __restrict__ list, const int* __restrict__ offs,
    const float* __restrict__ hgraph, const float* __restrict__ Wc,
    const float* __restrict__ bc, unsigned short* __restrict__ hatAb,
    float* __restrict__ S, float* __restrict__ Se,
    int* __restrict__ nzflags, int* __restrict__ counters,
    float* __restrict__ out)
{
  __shared__ int   sidx[256];
  __shared__ unsigned char sflag[256];
  __shared__ float wr4[4][4];
  __shared__ float wrc[TCLS][4];
  const int g = blockIdx.x;
  const int t = threadIdx.x;
  const int w = t >> 6, lane = t & 63;
  const int start = offs[g], end = offs[g+1];
  const int cnt = end - start;
  float sv = 0.f, sev = 0.f;
  int cv = 0, ce = 0;
  for (int base = 0; base < cnt; base += 256){
    const int nb = min(256, cnt - base);
    __syncthreads();
    if (t < nb){
      const int i = list[start + base + t];
      sidx[t] = i;
      const float m = mask[i];
      sflag[t] = (m > 0.4f) ? 1 : ((m <= 0.3f) ? 2 : 0);
    }
    __syncthreads();
    // 4-deep unrolled gather: independent loads pipeline under vmcnt
    for (int p = 0; p < nb; p += 4){
      const int lim = nb - p;
      float v0=0.f, v1=0.f, v2=0.f, v3=0.f;
      int f0=0, f1=0, f2=0, f3=0;
      f0 = sflag[p]; v0 = hsub[(size_t)sidx[p]*DIM + t];
      if (lim > 1){ f1 = sflag[p+1]; v1 = hsub[(size_t)sidx[p+1]*DIM + t]; }
      if (lim > 2){ f2 = sflag[p+2]; v2 = hsub[(size_t)sidx[p+2]*DIM + t]; }
      if (lim > 3){ f3 = sflag[p+3]; v3 = hsub[(size_t)sidx[p+3]*DIM + t]; }
      if (f0==1){ sv+=v0; cv++; } else if (f0==2){ sev+=v0; ce++; }
      if (f1==1){ sv+=v1; cv++; } else if (f1==2){ sev+=v1; ce++; }
      if (f2==1){ sv+=v2; cv++; } else if (f2==2){ sev+=v2; ce++; }
      if (f3==1){ sv+=v3; cv++; } else if (f3==2){ sev+=v3; ce++; }
    }
  }
  __syncthreads();
  const float aligned = sv  / fmaxf((float)cv, 1.f);
  const float envv    = sev / fmaxf((float)ce, 1.f);
  float r0 = wave_reduce(aligned*aligned);
  float r1 = wave_reduce(envv*envv);
  float r2 = wave_reduce(aligned != 0.f ? 1.f : 0.f);
  float r3 = wave_reduce(envv    != 0.f ? 1.f : 0.f);
  if (lane == 0){ wr4[w][0]=r0; wr4[w][1]=r1; wr4[w][2]=r2; wr4[w][3]=r3; }
  __syncthreads();
  const float an2  = wr4[0][0]+wr4[1][0]+wr4[2][0]+wr4[3][0];
  const float en2  = wr4[0][1]+wr4[1][1]+wr4[2][1]+wr4[3][1];
  const float nzpf = wr4[0][2]+wr4[1][2]+wr4[2][2]+wr4[3][2];
  const float nzef = wr4[0][3]+wr4[1][3]+wr4[2][3]+wr4[3][3];
  const bool nzp = nzpf > 0.f, nze = nzef > 0.f;
  const float an = fmaxf(sqrtf(an2), 1e-8f);
  const float en = fmaxf(sqrtf(en2), 1e-8f);
  const float ha = aligned / an;
  hatAb[(size_t)g*DIM + t] = (unsigned short)bf16_rne(ha);
  atomicAdd(&S[t], ha);
  if (nze) atomicAdd(&Se[t], envv / en);
  if (t == 0){
    nzflags[g] = nzp ? 1 : 0;
    if (nzp) atomicAdd(&counters[0], 1);
    if (nze) atomicAdd(&counters[1], 1);
  }
  const float hg = hgraph[(size_t)g*DIM + t];
  #pragma unroll
  for (int c = 0; c < TCLS; ++c){
    float part = hg*Wc[t*TCLS+c] + aligned*Wc[(DIM+t)*TCLS+c];
    part = wave_reduce(part);
    if (lane == 0) wrc[c][w] = part;
  }
  __syncthreads();
  if (t < TCLS)
    out[g*TCLS + t] = wrc[t][0]+wrc[t][1]+wrc[t][2]+wrc[t][3] + bc[t];
}

// ---------------- kernel D: contrastive loss via rank-1 identity ----------------
__global__ __launch_bounds__(256) void loss_kernel(
    const unsigned short* __restrict__ hatAb, const float* __restrict__ S,
    const float* __restrict__ Se, const int* __restrict__ nzflags,
    const int* __restrict__ counters, float* __restrict__ loss)
{
  __shared__ float wr[4][2];
  const int g = blockIdx.x, t = threadIdx.x;
  const int w = t >> 6, lane = t & 63;
  const float ha = bf16_to_f((short)hatAb[(size_t)g*DIM + t]);
  float p0 = wave_reduce(ha*S[t]);
  float p1 = wave_reduce(ha*Se[t]);
  if (lane == 0){ wr[w][0] = p0; wr[w][1] = p1; }
  __syncthreads();
  if (t == 0){
    const float dS  = wr[0][0]+wr[1][0]+wr[2][0]+wr[3][0];
    const float dSe = wr[0][1]+wr[1][1]+wr[2][1]+wr[3][1];
    const int nzp_cnt = counters[0];
    const int nenv = counters[1];
    const float pos_num = fmaxf((float)(nzp_cnt - 1), 1.f);
    const float positive = (4096.f - dS) / pos_num;
    const float negative = ((float)nenv - dSe) / fmaxf((float)nenv, 1.f);
    float contrib = fmaxf(positive - negative + 1.f, 0.f);
    contrib *= (nzflags[g] ? 1.f : 0.f) * ((nenv > 0) ? 1.f : 0.f);
    atomicAdd(loss, contrib * (1.f/4096.f));
  }
}

// ---------------- launch ----------------
extern "C" void kernel_launch(void* const* d_in, const int* in_sizes, int n_in,
                              void* d_out, int out_size, void* d_ws, size_t ws_size,
                              hipStream_t stream) {
  const float* h_graph = (const float*)d_in[0];
  const float* h_sub   = (const float*)d_in[1];
  const float* W1      = (const float*)d_in[2];
  const float* b1      = (const float*)d_in[3];
  const float* W2      = (const float*)d_in[4];
  const float* b2      = (const float*)d_in[5];
  const float* Wc      = (const float*)d_in[6];
  const float* bc      = (const float*)d_in[7];
  const int*   s2g     = (const int*)d_in[8];

  float* out  = (float*)d_out;          // [4096,10]
  float* loss = out + N_GR*TCLS;        // scalar
  float* mask = loss + 1;               // [200000]

  // workspace layout — ~3.5 MB (proven-safe)
  char* ws = (char*)d_ws;
  short* bth    = (short*)ws;                          // 256 KB
  short* btl    = bth + HID*DIM;                       // 256 KB
  unsigned short* hatAb = (unsigned short*)(btl + HID*DIM);  // 2 MB
  int* cnt_all  = (int*)(hatAb + (size_t)N_GR*DIM);    // 4096
  int* offs     = cnt_all + N_GR;                      // 4097
  int* cursor   = offs + N_GR + 1;                     // 4096
  int* list     = cursor + N_GR;                       // 200000
  int* nzflags  = list + N_SUB;                        // 4096
  int* counters = nzflags + N_GR;                      // 2
  int* rcnt     = counters + 2;                        // 1
  int* rlist    = rcnt + 1;                            // 16384
  float* S      = (float*)(rlist + RCAP);              // 256
  float* Se     = S + DIM;                             // 256

  hipLaunchKernelGGL(init_kernel, dim3(16), dim3(256), 0, stream,
                     cnt_all, S, Se, counters, loss, rcnt);
  hipLaunchKernelGGL(bconv_kernel, dim3(HID*DIM/256), dim3(256), 0, stream,
                     W1, bth, btl);
  hipLaunchKernelGGL(mask_gemm, dim3(N_SUB/64), dim3(512), 0, stream,
                     h_sub, bth, btl, b1, W2, b2, s2g, mask, cnt_all, rlist, rcnt);
  hipLaunchKernelGGL(refine_kernel, dim3(384), dim3(256), 0, stream,
                     h_sub, W1, b1, W2, b2, rlist, rcnt, mask);
  hipLaunchKernelGGL(scan_kernel, dim3(1), dim3(1024), 0, stream,
                     cnt_all, offs, cursor);
  hipLaunchKernelGGL(fill_kernel, dim3((N_SUB+255)/256), dim3(256), 0, stream,
                     s2g, cursor, list);
  hipLaunchKernelGGL(graph_means, dim3(N_GR), dim3(256), 0, stream,
                     h_sub, mask, list, offs, h_graph, Wc, bc,
                     hatAb, S, Se, nzflags, counters, out);
  hipLaunchKernelGGL(loss_kernel, dim3(N_GR), dim3(256), 0, stream,
                     hatAb, S, Se, nzflags, counters, loss);
}

// Round 12
// 470.721 us; speedup vs baseline: 8.4459x; 1.0522x over previous
//
#include <hip/hip_runtime.h>

#define N_SUB 200000
#define N_GR  4096
#define DIM   256
#define HID   512
#define TCLS  10
#define KH    128            // K-half staged per phase
#define MROWS 128            // rows per block (2x round-11)
#define RCAP  16384
#define RMARG 1e-3f

typedef __attribute__((ext_vector_type(8))) short short8;
typedef __attribute__((ext_vector_type(4))) float f32x4;

__device__ __forceinline__ short bf16_rne(float x){
  unsigned u = __builtin_bit_cast(unsigned, x);
  unsigned r = (u + 0x7FFFu + ((u >> 16) & 1u)) >> 16;
  return (short)r;
}
__device__ __forceinline__ float bf16_to_f(short h){
  unsigned u = ((unsigned)(unsigned short)h) << 16;
  return __builtin_bit_cast(float, u);
}
__device__ __forceinline__ float wave_reduce(float v){
  #pragma unroll
  for (int d = 1; d < 64; d <<= 1) v += __shfl_xor(v, d, 64);
  return v;
}
// swizzled fragment-major A granule index (16B granules); mt 0..7
__device__ __forceinline__ int a_gran(int mt, int mrow, int ks, int kgrp){
  return (((((mt*4 + ks)*4 + kgrp)*2 + (mrow>>3)) << 3)
          | ((mrow & 7) ^ (ks << 1) ^ (kgrp & 1)));
}

__device__ __forceinline__ float block_reduce_sum_256(float v, float* red){
  int t = threadIdx.x;
  red[t] = v; __syncthreads();
  #pragma unroll
  for (int s = 128; s > 0; s >>= 1){
    if (t < s) red[t] += red[t+s];
    __syncthreads();
  }
  float r = red[0];
  __syncthreads();
  return r;
}

// ---------------- init (graph replays -> zero every call) ----------------
__global__ void init_kernel(int* cnt_all, float* S, float* Se, int* counters,
                            float* loss, int* rcnt){
  int i = blockIdx.x*blockDim.x + threadIdx.x;
  if (i < N_GR) cnt_all[i] = 0;
  if (i < DIM){ S[i] = 0.f; Se[i] = 0.f; }
  if (i < 2) counters[i] = 0;
  if (i == 0){ loss[0] = 0.f; rcnt[0] = 0; }
}

// ---------------- W1 -> fragment-major packed bf16 hi/lo ----------------
// dst: [nt 0..31][ksg 0..7][lane 0..63][kk 0..7]; lane = kgrp*16 + mrow
__global__ __launch_bounds__(256) void bconv_kernel(const float* __restrict__ W1,
                                                    short* __restrict__ bth,
                                                    short* __restrict__ btl){
  const int i = blockIdx.x*256 + threadIdx.x;
  const int k = i >> 9;
  const int j = i & 511;
  const float x = W1[i];
  const short h = bf16_rne(x);
  const short l = bf16_rne(x - bf16_to_f(h));
  const int nt = j >> 4, mrow = j & 15;
  const int ksg = k >> 5, kgrp = (k >> 3) & 3, kk = k & 7;
  const int lane = kgrp*16 + mrow;
  const size_t dst = (((size_t)(nt*8 + ksg)*64 + lane) << 3) + kk;
  bth[dst] = h;
  btl[dst] = l;
}

// ---------------- kernel A: MFMA 3-term split, 128 rows/block ----------------
// 512 thr = 8 waves; wave q owns cols [q*64, q*64+64); acc[8][4] (8 m-tiles).
__global__ __launch_bounds__(512) void mask_gemm(
    const float* __restrict__ hsub, const short* __restrict__ bth,
    const short* __restrict__ btl, const float* __restrict__ b1,
    const float* __restrict__ W2, const float* __restrict__ b2,
    const int* __restrict__ s2g, float* __restrict__ mask_out,
    int* __restrict__ cnt_all, int* __restrict__ rlist, int* __restrict__ rcnt)
{
  __shared__ short a_hi[16384];     // 32 KB swizzled fragment-major (128 rows x 128 k)
  __shared__ short a_lo[16384];     // 32 KB
  __shared__ float sred[1024];      // 4 KB
  const int tid = threadIdx.x;
  const int lane = tid & 63;
  const int q = tid >> 6;
  const int mrow = lane & 15;
  const int kgrp = lane >> 4;

  f32x4 acc[8][4];
  #pragma unroll
  for (int mt=0; mt<8; ++mt)
    #pragma unroll
    for (int nt=0; nt<4; ++nt) acc[mt][nt] = (f32x4){0.f,0.f,0.f,0.f};

  const int brow = blockIdx.x*MROWS;

#define STAGE(PH)                                                              \
  { _Pragma("unroll")                                                          \
    for (int i = 0; i < 8; ++i){                                               \
      const int idx = i*512 + tid;          /* chunk 0..4095 */                \
      const int rr = idx >> 5;              /* row 0..127 */                   \
      const int ch = idx & 31;                                                 \
      const int grow = min(brow + rr, N_SUB-1);                                \
      const float4 v = *reinterpret_cast<const float4*>(                       \
          hsub + (size_t)grow*DIM + (PH)*KH + ch*4);                           \
      const short h0=bf16_rne(v.x), h1=bf16_rne(v.y), h2=bf16_rne(v.z), h3=bf16_rne(v.w); \
      const short l0=bf16_rne(v.x-bf16_to_f(h0)), l1=bf16_rne(v.y-bf16_to_f(h1)); \
      const short l2=bf16_rne(v.z-bf16_to_f(h2)), l3=bf16_rne(v.w-bf16_to_f(h3)); \
      const int so = a_gran(rr>>4, rr&15, ch>>3, (ch>>1)&3)*8 + (ch&1)*4;      \
      *reinterpret_cast<short4*>(&a_hi[so]) = make_short4(h0,h1,h2,h3);        \
      *reinterpret_cast<short4*>(&a_lo[so]) = make_short4(l0,l1,l2,l3);        \
    } }

#define LOADB(KSG)                                                             \
  { _Pragma("unroll")                                                          \
    for (int nt=0; nt<4; ++nt){                                                \
      const size_t bo = (((size_t)((q*4+nt)*8 + (KSG))*64 + lane) << 3);       \
      Bh[nt] = *reinterpret_cast<const short8*>(bth + bo);                     \
      Bl[nt] = *reinterpret_cast<const short8*>(btl + bo);                     \
    } }

#define LOADA(KS, MG)                                                          \
  { _Pragma("unroll")                                                          \
    for (int m=0; m<4; ++m){                                                   \
      const int so = a_gran((MG)*4+m, mrow, (KS), kgrp)*8;                     \
      Ah[m] = *reinterpret_cast<const short8*>(&a_hi[so]);                     \
      Al[m] = *reinterpret_cast<const short8*>(&a_lo[so]);                     \
    } }

#define MFMA3(MG)                                                              \
  { _Pragma("unroll")                                                          \
    for (int nt=0; nt<4; ++nt){                                                \
      _Pragma("unroll")                                                        \
      for (int m=0; m<4; ++m){                                                 \
        acc[(MG)*4+m][nt] = __builtin_amdgcn_mfma_f32_16x16x32_bf16(Ah[m], Bh[nt], acc[(MG)*4+m][nt], 0,0,0); \
        acc[(MG)*4+m][nt] = __builtin_amdgcn_mfma_f32_16x16x32_bf16(Ah[m], Bl[nt], acc[(MG)*4+m][nt], 0,0,0); \
        acc[(MG)*4+m][nt] = __builtin_amdgcn_mfma_f32_16x16x32_bf16(Al[m], Bh[nt], acc[(MG)*4+m][nt], 0,0,0); \
      } } }

  short8 Bh[4], Bl[4], Ah[4], Al[4];
  #pragma unroll
  for (int ph = 0; ph < 2; ++ph){
    __syncthreads();   // prior-phase LDS reads done before overwrite
    STAGE(ph);
    __syncthreads();
    #pragma unroll
    for (int ks = 0; ks < 4; ++ks){
      LOADB(ph*4 + ks);
      LOADA(ks, 0); MFMA3(0);
      LOADA(ks, 1); MFMA3(1);
    }
  }

  // ---- epilogue: bias + ReLU + W2 dot; reduce 16 n-lanes; combine 8 waves ----
  float w2v[4], b1v[4];
  #pragma unroll
  for (int nt=0; nt<4; ++nt){
    const int n = q*64 + nt*16 + mrow;    // C: col = lane&15
    w2v[nt] = W2[n]; b1v[nt] = b1[n];
  }
  #pragma unroll
  for (int mt=0; mt<8; ++mt){
    #pragma unroll
    for (int r=0; r<4; ++r){
      float s = 0.f;
      #pragma unroll
      for (int nt=0; nt<4; ++nt)
        s += fmaxf(acc[mt][nt][r] + b1v[nt], 0.f) * w2v[nt];
      s += __shfl_xor(s, 1, 64);
      s += __shfl_xor(s, 2, 64);
      s += __shfl_xor(s, 4, 64);
      s += __shfl_xor(s, 8, 64);
      if (mrow == 0)
        sred[q*128 + mt*16 + kgrp*4 + r] = s;   // C: row = (lane>>4)*4 + reg
    }
  }
  __syncthreads();
  if (tid < MROWS){
    const int rr = brow + tid;
    if (rr < N_SUB){
      float tot = b2[0];
      #pragma unroll
      for (int w = 0; w < 8; ++w) tot += sred[w*128 + tid];
      const float m = 1.f / (1.f + expf(-tot));
      mask_out[rr] = m;
      atomicAdd(&cnt_all[s2g[rr]], 1);
      if (fabsf(m - 0.4f) < RMARG || fabsf(m - 0.3f) < RMARG){
        const int p = atomicAdd(rcnt, 1);
        if (p < RCAP) rlist[p] = rr;
      }
    }
  }
#undef STAGE
#undef LOADB
#undef LOADA
#undef MFMA3
}

// ---------------- refine: exact fp32 logit for borderline rows ----------------
__global__ __launch_bounds__(256) void refine_kernel(
    const float* __restrict__ hsub, const float* __restrict__ W1,
    const float* __restrict__ b1, const float* __restrict__ W2,
    const float* __restrict__ b2, const int* __restrict__ rlist,
    const int* __restrict__ rcnt, float* __restrict__ mask_out)
{
  __shared__ float arow[256];
  __shared__ float red[256];
  const int n = min(rcnt[0], RCAP);
  const int t = threadIdx.x;
  for (int it = blockIdx.x; it < n; it += gridDim.x){
    const int row = rlist[it];
    arow[t] = hsub[(size_t)row*DIM + t];
    __syncthreads();
    float s = 0.f;
    #pragma unroll
    for (int jj = 0; jj < 2; ++jj){
      const int j = jj*256 + t;
      float y = b1[j];
      for (int k = 0; k < 256; ++k)
        y = fmaf(arow[k], W1[(size_t)k*512 + j], y);
      s += fmaxf(y, 0.f) * W2[j];
    }
    const float tot = block_reduce_sum_256(s, red);
    if (t == 0) mask_out[row] = 1.f / (1.f + expf(-(tot + b2[0])));
    __syncthreads();
  }
}

// ---------------- CSR build: scan + fill ----------------
__global__ __launch_bounds__(1024) void scan_kernel(const int* __restrict__ cnt,
                                                    int* __restrict__ offs,
                                                    int* __restrict__ cursor){
  __shared__ int buf[1024];
  const int t = threadIdx.x;
  const int c0 = cnt[t*4], c1 = cnt[t*4+1], c2 = cnt[t*4+2], c3 = cnt[t*4+3];
  const int s = c0+c1+c2+c3;
  buf[t] = s; __syncthreads();
  for (int d = 1; d < 1024; d <<= 1){
    int v = (t >= d) ? buf[t-d] : 0;
    __syncthreads();
    buf[t] += v;
    __syncthreads();
  }
  const int excl = buf[t] - s;
  const int o0 = excl, o1 = excl+c0, o2 = o1+c1, o3 = o2+c2;
  offs[t*4]=o0; offs[t*4+1]=o1; offs[t*4+2]=o2; offs[t*4+3]=o3;
  cursor[t*4]=o0; cursor[t*4+1]=o1; cursor[t*4+2]=o2; cursor[t*4+3]=o3;
  if (t == 1023) offs[4096] = buf[1023];
}

__global__ void fill_kernel(const int* __restrict__ s2g, int* __restrict__ cursor,
                            int* __restrict__ list){
  const int i = blockIdx.x*blockDim.x + threadIdx.x;
  if (i < N_SUB){
    const int g = s2g[i];
    const int p = atomicAdd(&cursor[g], 1);
    list[p] = i;
  }
}

// ---------------- kernel C: per-graph masked means (batched gather) ----------------
__global__ __launch_bounds__(256) void graph_means(
    const float* __restrict__ hsub, const float* __restrict__ mask,
    const int* __restrict__ list, const int* __restrict__ offs,
    const float* __restrict__ hgraph, const float* __restrict__ Wc,
    const float* __restrict__ bc, unsigned short* __restrict__ hatAb,
    float* __restrict__ S, float* __restrict__ Se,
    int* __restrict__ nzflags, int* __restrict__ counters,
    float* __restrict__ out)
{
  __shared__ int   sidx[256];
  __shared__ unsigned char sflag[256];
  __shared__ float wr4[4][4];
  __shared__ float wrc[TCLS][4];
  const int g = blockIdx.x;
  const int t = threadIdx.x;
  const int w = t >> 6, lane = t & 63;
  const int start = offs[g], end = offs[g+1];
  const int cnt = end - start;
  float sv = 0.f, sev = 0.f;
  int cv = 0, ce = 0;
  for (int base = 0; base < cnt; base += 256){
    const int nb = min(256, cnt - base);
    __syncthreads();
    if (t < nb){
      const int i = list[start + base + t];
      sidx[t] = i;
      const float m = mask[i];
      sflag[t] = (m > 0.4f) ? 1 : ((m <= 0.3f) ? 2 : 0);
    }
    __syncthreads();
    for (int p = 0; p < nb; p += 4){
      const int lim = nb - p;
      float v0=0.f, v1=0.f, v2=0.f, v3=0.f;
      int f0=0, f1=0, f2=0, f3=0;
      f0 = sflag[p]; v0 = hsub[(size_t)sidx[p]*DIM + t];
      if (lim > 1){ f1 = sflag[p+1]; v1 = hsub[(size_t)sidx[p+1]*DIM + t]; }
      if (lim > 2){ f2 = sflag[p+2]; v2 = hsub[(size_t)sidx[p+2]*DIM + t]; }
      if (lim > 3){ f3 = sflag[p+3]; v3 = hsub[(size_t)sidx[p+3]*DIM + t]; }
      if (f0==1){ sv+=v0; cv++; } else if (f0==2){ sev+=v0; ce++; }
      if (f1==1){ sv+=v1; cv++; } else if (f1==2){ sev+=v1; ce++; }
      if (f2==1){ sv+=v2; cv++; } else if (f2==2){ sev+=v2; ce++; }
      if (f3==1){ sv+=v3; cv++; } else if (f3==2){ sev+=v3; ce++; }
    }
  }
  __syncthreads();
  const float aligned = sv  / fmaxf((float)cv, 1.f);
  const float envv    = sev / fmaxf((float)ce, 1.f);
  float r0 = wave_reduce(aligned*aligned);
  float r1 = wave_reduce(envv*envv);
  float r2 = wave_reduce(aligned != 0.f ? 1.f : 0.f);
  float r3 = wave_reduce(envv    != 0.f ? 1.f : 0.f);
  if (lane == 0){ wr4[w][0]=r0; wr4[w][1]=r1; wr4[w][2]=r2; wr4[w][3]=r3; }
  __syncthreads();
  const float an2  = wr4[0][0]+wr4[1][0]+wr4[2][0]+wr4[3][0];
  const float en2  = wr4[0][1]+wr4[1][1]+wr4[2][1]+wr4[3][1];
  const float nzpf = wr4[0][2]+wr4[1][2]+wr4[2][2]+wr4[3][2];
  const float nzef = wr4[0][3]+wr4[1][3]+wr4[2][3]+wr4[3][3];
  const bool nzp = nzpf > 0.f, nze = nzef > 0.f;
  const float an = fmaxf(sqrtf(an2), 1e-8f);
  const float en = fmaxf(sqrtf(en2), 1e-8f);
  const float ha = aligned / an;
  hatAb[(size_t)g*DIM + t] = (unsigned short)bf16_rne(ha);
  atomicAdd(&S[t], ha);
  if (nze) atomicAdd(&Se[t], envv / en);
  if (t == 0){
    nzflags[g] = nzp ? 1 : 0;
    if (nzp) atomicAdd(&counters[0], 1);
    if (nze) atomicAdd(&counters[1], 1);
  }
  const float hg = hgraph[(size_t)g*DIM + t];
  #pragma unroll
  for (int c = 0; c < TCLS; ++c){
    float part = hg*Wc[t*TCLS+c] + aligned*Wc[(DIM+t)*TCLS+c];
    part = wave_reduce(part);
    if (lane == 0) wrc[c][w] = part;
  }
  __syncthreads();
  if (t < TCLS)
    out[g*TCLS + t] = wrc[t][0]+wrc[t][1]+wrc[t][2]+wrc[t][3] + bc[t];
}

// ---------------- kernel D: contrastive loss via rank-1 identity ----------------
__global__ __launch_bounds__(256) void loss_kernel(
    const unsigned short* __restrict__ hatAb, const float* __restrict__ S,
    const float* __restrict__ Se, const int* __restrict__ nzflags,
    const int* __restrict__ counters, float* __restrict__ loss)
{
  __shared__ float wr[4][2];
  const int g = blockIdx.x, t = threadIdx.x;
  const int w = t >> 6, lane = t & 63;
  const float ha = bf16_to_f((short)hatAb[(size_t)g*DIM + t]);
  float p0 = wave_reduce(ha*S[t]);
  float p1 = wave_reduce(ha*Se[t]);
  if (lane == 0){ wr[w][0] = p0; wr[w][1] = p1; }
  __syncthreads();
  if (t == 0){
    const float dS  = wr[0][0]+wr[1][0]+wr[2][0]+wr[3][0];
    const float dSe = wr[0][1]+wr[1][1]+wr[2][1]+wr[3][1];
    const int nzp_cnt = counters[0];
    const int nenv = counters[1];
    const float pos_num = fmaxf((float)(nzp_cnt - 1), 1.f);
    const float positive = (4096.f - dS) / pos_num;
    const float negative = ((float)nenv - dSe) / fmaxf((float)nenv, 1.f);
    float contrib = fmaxf(positive - negative + 1.f, 0.f);
    contrib *= (nzflags[g] ? 1.f : 0.f) * ((nenv > 0) ? 1.f : 0.f);
    atomicAdd(loss, contrib * (1.f/4096.f));
  }
}

// ---------------- launch ----------------
extern "C" void kernel_launch(void* const* d_in, const int* in_sizes, int n_in,
                              void* d_out, int out_size, void* d_ws, size_t ws_size,
                              hipStream_t stream) {
  const float* h_graph = (const float*)d_in[0];
  const float* h_sub   = (const float*)d_in[1];
  const float* W1      = (const float*)d_in[2];
  const float* b1      = (const float*)d_in[3];
  const float* W2      = (const float*)d_in[4];
  const float* b2      = (const float*)d_in[5];
  const float* Wc      = (const float*)d_in[6];
  const float* bc      = (const float*)d_in[7];
  const int*   s2g     = (const int*)d_in[8];

  float* out  = (float*)d_out;          // [4096,10]
  float* loss = out + N_GR*TCLS;        // scalar
  float* mask = loss + 1;               // [200000]

  // workspace layout — ~3.5 MB (proven-safe)
  char* ws = (char*)d_ws;
  short* bth    = (short*)ws;                          // 256 KB
  short* btl    = bth + HID*DIM;                       // 256 KB
  unsigned short* hatAb = (unsigned short*)(btl + HID*DIM);  // 2 MB
  int* cnt_all  = (int*)(hatAb + (size_t)N_GR*DIM);    // 4096
  int* offs     = cnt_all + N_GR;                      // 4097
  int* cursor   = offs + N_GR + 1;                     // 4096
  int* list     = cursor + N_GR;                       // 200000
  int* nzflags  = list + N_SUB;                        // 4096
  int* counters = nzflags + N_GR;                      // 2
  int* rcnt     = counters + 2;                        // 1
  int* rlist    = rcnt + 1;                            // 16384
  float* S      = (float*)(rlist + RCAP);              // 256
  float* Se     = S + DIM;                             // 256

  hipLaunchKernelGGL(init_kernel, dim3(16), dim3(256), 0, stream,
                     cnt_all, S, Se, counters, loss, rcnt);
  hipLaunchKernelGGL(bconv_kernel, dim3(HID*DIM/256), dim3(256), 0, stream,
                     W1, bth, btl);
  hipLaunchKernelGGL(mask_gemm, dim3((N_SUB + MROWS - 1)/MROWS), dim3(512), 0, stream,
                     h_sub, bth, btl, b1, W2, b2, s2g, mask, cnt_all, rlist, rcnt);
  hipLaunchKernelGGL(refine_kernel, dim3(384), dim3(256), 0, stream,
                     h_sub, W1, b1, W2, b2, rlist, rcnt, mask);
  hipLaunchKernelGGL(scan_kernel, dim3(1), dim3(1024), 0, stream,
                     cnt_all, offs, cursor);
  hipLaunchKernelGGL(fill_kernel, dim3((N_SUB+255)/256), dim3(256), 0, stream,
                     s2g, cursor, list);
  hipLaunchKernelGGL(graph_means, dim3(N_GR), dim3(256), 0, stream,
                     h_sub, mask, list, offs, h_graph, Wc, bc,
                     hatAb, S, Se, nzflags, counters, out);
  hipLaunchKernelGGL(loss_kernel, dim3(N_GR), dim3(256), 0, stream,
                     hatAb, S, Se, nzflags, counters, loss);
}

// Round 15
// 465.230 us; speedup vs baseline: 8.5456x; 1.0118x over previous
//
#include <hip/hip_runtime.h>

#define N_SUB 200000
#define N_GR  4096
#define DIM   256
#define HID   512
#define TCLS  10
#define MROWS 64             // 3125 * 64 = 200000 exactly (no tail)
#define RCAP  16384
#define RMARG 1e-3f

typedef __attribute__((ext_vector_type(8))) short short8;
typedef __attribute__((ext_vector_type(4))) float f32x4;

__device__ __forceinline__ short bf16_rne(float x){
  unsigned u = __builtin_bit_cast(unsigned, x);
  unsigned r = (u + 0x7FFFu + ((u >> 16) & 1u)) >> 16;
  return (short)r;
}
__device__ __forceinline__ float bf16_to_f(short h){
  unsigned u = ((unsigned)(unsigned short)h) << 16;
  return __builtin_bit_cast(float, u);
}
__device__ __forceinline__ float wave_reduce(float v){
  #pragma unroll
  for (int d = 1; d < 64; d <<= 1) v += __shfl_xor(v, d, 64);
  return v;
}
// swizzled fragment-major A granule index (16B granules); ks 0..7, mt 0..3
// high bits bijective over (mt,ks,kgrp,mrow>>3); low 3 = (mrow&7) XOR spread
__device__ __forceinline__ int a_gran(int mt, int mrow, int ks, int kgrp){
  return (((((mt*8 + ks)*4 + kgrp)*2 + (mrow>>3)) << 3)
          | ((mrow & 7) ^ ((ks & 3) << 1) ^ (kgrp & 1)));
}
__device__ __forceinline__ float block_reduce_sum_256(float v, float* red){
  int t = threadIdx.x;
  red[t] = v; __syncthreads();
  #pragma unroll
  for (int s = 128; s > 0; s >>= 1){
    if (t < s) red[t] += red[t+s];
    __syncthreads();
  }
  float r = red[0];
  __syncthreads();
  return r;
}

// ---------------- init ----------------
__global__ void init_kernel(int* cnt_all, float* S, float* Se, int* counters,
                            float* loss, int* rcnt){
  int i = blockIdx.x*blockDim.x + threadIdx.x;
  if (i < N_GR) cnt_all[i] = 0;
  if (i < DIM){ S[i] = 0.f; Se[i] = 0.f; }
  if (i < 2) counters[i] = 0;
  if (i == 0){ loss[0] = 0.f; rcnt[0] = 0; }
}

// ---------------- W1 -> fragment-major packed bf16 hi/lo ----------------
__global__ __launch_bounds__(256) void bconv_kernel(const float* __restrict__ W1,
                                                    short* __restrict__ bth,
                                                    short* __restrict__ btl){
  const int i = blockIdx.x*256 + threadIdx.x;
  const int k = i >> 9;
  const int j = i & 511;
  const float x = W1[i];
  const short h = bf16_rne(x);
  const short l = bf16_rne(x - bf16_to_f(h));
  const int nt = j >> 4, mrow = j & 15;
  const int ksg = k >> 5, kgrp = (k >> 3) & 3, kk = k & 7;
  const int lane = kgrp*16 + mrow;
  const size_t dst = (((size_t)(nt*8 + ksg)*64 + lane) << 3) + kk;
  bth[dst] = h;
  btl[dst] = l;
}

// ---------------- kernel A: manual-staged full-K 3-term MFMA (round-10 staging) ----------------
// 512 thr = 8 waves; 64 rows/block; K=256 resident; single stage, 2 barriers total.
__global__ __launch_bounds__(512) void mask_gemm(
    const float* __restrict__ hsub, const short* __restrict__ bth,
    const short* __restrict__ btl, const float* __restrict__ b1,
    const float* __restrict__ W2, const float* __restrict__ b2,
    const int* __restrict__ s2g, float* __restrict__ mask_out,
    int* __restrict__ cnt_all, int* __restrict__ rlist, int* __restrict__ rcnt)
{
  __shared__ short a_hi[16384];     // 32 KB swizzled fragment-major (64 rows x 256 k)
  __shared__ short a_lo[16384];     // 32 KB
  __shared__ float sred[512];       // 2 KB  -> 66 KB total (round-6-proven)
  const int tid = threadIdx.x;
  const int lane = tid & 63;
  const int q = tid >> 6;
  const int mrow = lane & 15;
  const int kgrp = lane >> 4;
  const int brow = blockIdx.x*MROWS;

  f32x4 acc[4][4];
  #pragma unroll
  for (int mt=0; mt<4; ++mt)
    #pragma unroll
    for (int nt=0; nt<4; ++nt) acc[mt][nt] = (f32x4){0.f,0.f,0.f,0.f};

  // ---- stage: hoist 8 coalesced float4 loads, then convert+swizzled ds_write ----
  const float* __restrict__ gbase = hsub + (size_t)brow*DIM;
  float4 g[8];
  #pragma unroll
  for (int i = 0; i < 8; ++i){
    const int idx = i*512 + tid;               // float4 chunk 0..4095
    g[i] = *reinterpret_cast<const float4*>(gbase + (size_t)idx*4);
  }
  #pragma unroll
  for (int i = 0; i < 8; ++i){
    const int idx = i*512 + tid;
    const int rr = idx >> 6;                   // row 0..63
    const int ch = idx & 63;                   // full-K chunk 0..63
    const float4 v = g[i];
    const short h0=bf16_rne(v.x), h1=bf16_rne(v.y), h2=bf16_rne(v.z), h3=bf16_rne(v.w);
    const short l0=bf16_rne(v.x-bf16_to_f(h0)), l1=bf16_rne(v.y-bf16_to_f(h1));
    const short l2=bf16_rne(v.z-bf16_to_f(h2)), l3=bf16_rne(v.w-bf16_to_f(h3));
    const int so = a_gran(rr>>4, rr&15, ch>>3, (ch>>1)&3)*8 + (ch&1)*4;
    *reinterpret_cast<short4*>(&a_hi[so]) = make_short4(h0,h1,h2,h3);
    *reinterpret_cast<short4*>(&a_lo[so]) = make_short4(l0,l1,l2,l3);
  }
  __syncthreads();

#define LOADB(KSG)                                                            \
  { _Pragma("unroll")                                                         \
    for (int nt=0; nt<4; ++nt){                                               \
      const size_t bo = (((size_t)((q*4+nt)*8 + (KSG))*64 + lane) << 3);      \
      Bh[nt] = *reinterpret_cast<const short8*>(bth + bo);                    \
      Bl[nt] = *reinterpret_cast<const short8*>(btl + bo);                    \
    } }

  short8 Bh[4], Bl[4];
  #pragma unroll
  for (int ks = 0; ks < 8; ++ks){
    LOADB(ks);
    #pragma unroll
    for (int m = 0; m < 4; ++m){
      const int so = a_gran(m, mrow, ks, kgrp)*8;
      const short8 Ah = *reinterpret_cast<const short8*>(&a_hi[so]);
      const short8 Al = *reinterpret_cast<const short8*>(&a_lo[so]);
      #pragma unroll
      for (int nt=0; nt<4; ++nt){
        acc[m][nt] = __builtin_amdgcn_mfma_f32_16x16x32_bf16(Ah, Bh[nt], acc[m][nt], 0,0,0);
        acc[m][nt] = __builtin_amdgcn_mfma_f32_16x16x32_bf16(Ah, Bl[nt], acc[m][nt], 0,0,0);
        acc[m][nt] = __builtin_amdgcn_mfma_f32_16x16x32_bf16(Al, Bh[nt], acc[m][nt], 0,0,0);
      }
    }
  }

  // ---- epilogue: bias + ReLU + W2 dot; reduce 16 n-lanes; combine 8 waves ----
  float w2v[4], b1v[4];
  #pragma unroll
  for (int nt=0; nt<4; ++nt){
    const int n = q*64 + nt*16 + mrow;    // C: col = lane&15
    w2v[nt] = W2[n]; b1v[nt] = b1[n];
  }
  #pragma unroll
  for (int mt=0; mt<4; ++mt){
    #pragma unroll
    for (int r=0; r<4; ++r){
      float s = 0.f;
      #pragma unroll
      for (int nt=0; nt<4; ++nt)
        s += fmaxf(acc[mt][nt][r] + b1v[nt], 0.f) * w2v[nt];
      s += __shfl_xor(s, 1, 64);
      s += __shfl_xor(s, 2, 64);
      s += __shfl_xor(s, 4, 64);
      s += __shfl_xor(s, 8, 64);
      if (mrow == 0)
        sred[q*64 + mt*16 + kgrp*4 + r] = s;   // C: row = (lane>>4)*4 + reg
    }
  }
  __syncthreads();
  if (tid < MROWS){
    const int rr = brow + tid;
    float tot = b2[0];
    #pragma unroll
    for (int w = 0; w < 8; ++w) tot += sred[w*64 + tid];
    const float m = 1.f / (1.f + expf(-tot));
    mask_out[rr] = m;
    atomicAdd(&cnt_all[s2g[rr]], 1);
    if (fabsf(m - 0.4f) < RMARG || fabsf(m - 0.3f) < RMARG){
      const int p = atomicAdd(rcnt, 1);
      if (p < RCAP) rlist[p] = rr;
    }
  }
#undef LOADB
}

// ---------------- refine: exact fp32 logit for borderline rows ----------------
__global__ __launch_bounds__(256) void refine_kernel(
    const float* __restrict__ hsub, const float* __restrict__ W1,
    const float* __restrict__ b1, const float* __restrict__ W2,
    const float* __restrict__ b2, const int* __restrict__ rlist,
    const int* __restrict__ rcnt, float* __restrict__ mask_out)
{
  __shared__ float arow[256];
  __shared__ float red[256];
  const int n = min(rcnt[0], RCAP);
  const int t = threadIdx.x;
  for (int it = blockIdx.x; it < n; it += gridDim.x){
    const int row = rlist[it];
    arow[t] = hsub[(size_t)row*DIM + t];
    __syncthreads();
    float s = 0.f;
    #pragma unroll
    for (int jj = 0; jj < 2; ++jj){
      const int j = jj*256 + t;
      float y = b1[j];
      for (int k = 0; k < 256; ++k)
        y = fmaf(arow[k], W1[(size_t)k*512 + j], y);
      s += fmaxf(y, 0.f) * W2[j];
    }
    const float tot = block_reduce_sum_256(s, red);
    if (t == 0) mask_out[row] = 1.f / (1.f + expf(-(tot + b2[0])));
    __syncthreads();
  }
}

// ---------------- CSR build: scan + fill ----------------
__global__ __launch_bounds__(1024) void scan_kernel(const int* __restrict__ cnt,
                                                    int* __restrict__ offs,
                                                    int* __restrict__ cursor){
  __shared__ int buf[1024];
  const int t = threadIdx.x;
  const int c0 = cnt[t*4], c1 = cnt[t*4+1], c2 = cnt[t*4+2], c3 = cnt[t*4+3];
  const int s = c0+c1+c2+c3;
  buf[t] = s; __syncthreads();
  for (int d = 1; d < 1024; d <<= 1){
    int v = (t >= d) ? buf[t-d] : 0;
    __syncthreads();
    buf[t] += v;
    __syncthreads();
  }
  const int excl = buf[t] - s;
  const int o0 = excl, o1 = excl+c0, o2 = o1+c1, o3 = o2+c2;
  offs[t*4]=o0; offs[t*4+1]=o1; offs[t*4+2]=o2; offs[t*4+3]=o3;
  cursor[t*4]=o0; cursor[t*4+1]=o1; cursor[t*4+2]=o2; cursor[t*4+3]=o3;
  if (t == 1023) offs[4096] = buf[1023];
}

__global__ void fill_kernel(const int* __restrict__ s2g, int* __restrict__ cursor,
                            int* __restrict__ list){
  const int i = blockIdx.x*blockDim.x + threadIdx.x;
  if (i < N_SUB){
    const int g = s2g[i];
    const int p = atomicAdd(&cursor[g], 1);
    list[p] = i;
  }
}

// ---------------- kernel C: per-graph masked means (batched gather) ----------------
__global__ __launch_bounds__(256) void graph_means(
    const float* __restrict__ hsub, const float* __restrict__ mask,
    const int* __restrict__ list, const int* __restrict__ offs,
    const float* __restrict__ hgraph, const float* __restrict__ Wc,
    const float* __restrict__ bc, unsigned short* __restrict__ hatAb,
    float* __restrict__ S, float* __restrict__ Se,
    int* __restrict__ nzflags, int* __restrict__ counters,
    float* __restrict__ out)
{
  __shared__ int   sidx[256];
  __shared__ unsigned char sflag[256];
  __shared__ float wr4[4][4];
  __shared__ float wrc[TCLS][4];
  const int g = blockIdx.x;
  const int t = threadIdx.x;
  const int w = t >> 6, lane = t & 63;
  const int start = offs[g], end = offs[g+1];
  const int cnt = end - start;
  float sv = 0.f, sev = 0.f;
  int cv = 0, ce = 0;
  for (int base = 0; base < cnt; base += 256){
    const int nb = min(256, cnt - base);
    __syncthreads();
    if (t < nb){
      const int i = list[start + base + t];
      sidx[t] = i;
      const float m = mask[i];
      sflag[t] = (m > 0.4f) ? 1 : ((m <= 0.3f) ? 2 : 0);
    }
    __syncthreads();
    for (int p = 0; p < nb; p += 4){
      const int lim = nb - p;
      float v0=0.f, v1=0.f, v2=0.f, v3=0.f;
      int f0=0, f1=0, f2=0, f3=0;
      f0 = sflag[p]; v0 = hsub[(size_t)sidx[p]*DIM + t];
      if (lim > 1){ f1 = sflag[p+1]; v1 = hsub[(size_t)sidx[p+1]*DIM + t]; }
      if (lim > 2){ f2 = sflag[p+2]; v2 = hsub[(size_t)sidx[p+2]*DIM + t]; }
      if (lim > 3){ f3 = sflag[p+3]; v3 = hsub[(size_t)sidx[p+3]*DIM + t]; }
      if (f0==1){ sv+=v0; cv++; } else if (f0==2){ sev+=v0; ce++; }
      if (f1==1){ sv+=v1; cv++; } else if (f1==2){ sev+=v1; ce++; }
      if (f2==1){ sv+=v2; cv++; } else if (f2==2){ sev+=v2; ce++; }
      if (f3==1){ sv+=v3; cv++; } else if (f3==2){ sev+=v3; ce++; }
    }
  }
  __syncthreads();
  const float aligned = sv  / fmaxf((float)cv, 1.f);
  const float envv    = sev / fmaxf((float)ce, 1.f);
  float r0 = wave_reduce(aligned*aligned);
  float r1 = wave_reduce(envv*envv);
  float r2 = wave_reduce(aligned != 0.f ? 1.f : 0.f);
  float r3 = wave_reduce(envv    != 0.f ? 1.f : 0.f);
  if (lane == 0){ wr4[w][0]=r0; wr4[w][1]=r1; wr4[w][2]=r2; wr4[w][3]=r3; }
  __syncthreads();
  const float an2  = wr4[0][0]+wr4[1][0]+wr4[2][0]+wr4[3][0];
  const float en2  = wr4[0][1]+wr4[1][1]+wr4[2][1]+wr4[3][1];
  const float nzpf = wr4[0][2]+wr4[1][2]+wr4[2][2]+wr4[3][2];
  const float nzef = wr4[0][3]+wr4[1][3]+wr4[2][3]+wr4[3][3];
  const bool nzp = nzpf > 0.f, nze = nzef > 0.f;
  const float an = fmaxf(sqrtf(an2), 1e-8f);
  const float en = fmaxf(sqrtf(en2), 1e-8f);
  const float ha = aligned / an;
  hatAb[(size_t)g*DIM + t] = (unsigned short)bf16_rne(ha);
  atomicAdd(&S[t], ha);
  if (nze) atomicAdd(&Se[t], envv / en);
  if (t == 0){
    nzflags[g] = nzp ? 1 : 0;
    if (nzp) atomicAdd(&counters[0], 1);
    if (nze) atomicAdd(&counters[1], 1);
  }
  const float hg = hgraph[(size_t)g*DIM + t];
  #pragma unroll
  for (int c = 0; c < TCLS; ++c){
    float part = hg*Wc[t*TCLS+c] + aligned*Wc[(DIM+t)*TCLS+c];
    part = wave_reduce(part);
    if (lane == 0) wrc[c][w] = part;
  }
  __syncthreads();
  if (t < TCLS)
    out[g*TCLS + t] = wrc[t][0]+wrc[t][1]+wrc[t][2]+wrc[t][3] + bc[t];
}

// ---------------- kernel D: contrastive loss via rank-1 identity ----------------
__global__ __launch_bounds__(256) void loss_kernel(
    const unsigned short* __restrict__ hatAb, const float* __restrict__ S,
    const float* __restrict__ Se, const int* __restrict__ nzflags,
    const int* __restrict__ counters, float* __restrict__ loss)
{
  __shared__ float wr[4][2];
  const int g = blockIdx.x, t = threadIdx.x;
  const int w = t >> 6, lane = t & 63;
  const float ha = bf16_to_f((short)hatAb[(size_t)g*DIM + t]);
  float p0 = wave_reduce(ha*S[t]);
  float p1 = wave_reduce(ha*Se[t]);
  if (lane == 0){ wr[w][0] = p0; wr[w][1] = p1; }
  __syncthreads();
  if (t == 0){
    const float dS  = wr[0][0]+wr[1][0]+wr[2][0]+wr[3][0];
    const float dSe = wr[0][1]+wr[1][1]+wr[2][1]+wr[3][1];
    const int nzp_cnt = counters[0];
    const int nenv = counters[1];
    const float pos_num = fmaxf((float)(nzp_cnt - 1), 1.f);
    const float positive = (4096.f - dS) / pos_num;
    const float negative = ((float)nenv - dSe) / fmaxf((float)nenv, 1.f);
    float contrib = fmaxf(positive - negative + 1.f, 0.f);
    contrib *= (nzflags[g] ? 1.f : 0.f) * ((nenv > 0) ? 1.f : 0.f);
    atomicAdd(loss, contrib * (1.f/4096.f));
  }
}

// ---------------- launch ----------------
extern "C" void kernel_launch(void* const* d_in, const int* in_sizes, int n_in,
                              void* d_out, int out_size, void* d_ws, size_t ws_size,
                              hipStream_t stream) {
  const float* h_graph = (const float*)d_in[0];
  const float* h_sub   = (const float*)d_in[1];
  const float* W1      = (const float*)d_in[2];
  const float* b1      = (const float*)d_in[3];
  const float* W2      = (const float*)d_in[4];
  const float* b2      = (const float*)d_in[5];
  const float* Wc      = (const float*)d_in[6];
  const float* bc      = (const float*)d_in[7];
  const int*   s2g     = (const int*)d_in[8];

  float* out  = (float*)d_out;          // [4096,10]
  float* loss = out + N_GR*TCLS;        // scalar
  float* mask = loss + 1;               // [200000]

  // workspace layout — ~3.5 MB (proven-safe)
  char* ws = (char*)d_ws;
  short* bth    = (short*)ws;                          // 256 KB
  short* btl    = bth + HID*DIM;                       // 256 KB
  unsigned short* hatAb = (unsigned short*)(btl + HID*DIM);  // 2 MB
  int* cnt_all  = (int*)(hatAb + (size_t)N_GR*DIM);    // 4096
  int* offs     = cnt_all + N_GR;                      // 4097
  int* cursor   = offs + N_GR + 1;                     // 4096
  int* list     = cursor + N_GR;                       // 200000
  int* nzflags  = list + N_SUB;                        // 4096
  int* counters = nzflags + N_GR;                      // 2
  int* rcnt     = counters + 2;                        // 1
  int* rlist    = rcnt + 1;                            // 16384
  float* S      = (float*)(rlist + RCAP);              // 256
  float* Se     = S + DIM;                             // 256

  hipLaunchKernelGGL(init_kernel, dim3(16), dim3(256), 0, stream,
                     cnt_all, S, Se, counters, loss, rcnt);
  hipLaunchKernelGGL(bconv_kernel, dim3(HID*DIM/256), dim3(256), 0, stream,
                     W1, bth, btl);
  hipLaunchKernelGGL(mask_gemm, dim3(N_SUB/MROWS), dim3(512), 0, stream,
                     h_sub, bth, btl, b1, W2, b2, s2g, mask, cnt_all, rlist, rcnt);
  hipLaunchKernelGGL(refine_kernel, dim3(384), dim3(256), 0, stream,
                     h_sub, W1, b1, W2, b2, rlist, rcnt, mask);
  hipLaunchKernelGGL(scan_kernel, dim3(1), dim3(1024), 0, stream,
                     cnt_all, offs, cursor);
  hipLaunchKernelGGL(fill_kernel, dim3((N_SUB+255)/256), dim3(256), 0, stream,
                     s2g, cursor, list);
  hipLaunchKernelGGL(graph_means, dim3(N_GR), dim3(256), 0, stream,
                     h_sub, mask, list, offs, h_graph, Wc, bc,
                     hatAb, S, Se, nzflags, counters, out);
  hipLaunchKernelGGL(loss_kernel, dim3(N_GR), dim3(256), 0, stream,
                     hatAb, S, Se, nzflags, counters, loss);
}

// Round 18
// 456.466 us; speedup vs baseline: 8.7096x; 1.0192x over previous
//
#include <hip/hip_runtime.h>

#define N_SUB 200000
#define N_GR  4096
#define DIM   256
#define HID   512
#define TCLS  10
#define MROWS 64             // 3125 * 64 = 200000 exactly (no tail)
#define RCAP  16384
#define RMARG 1e-3f

typedef __attribute__((ext_vector_type(8))) short short8;
typedef __attribute__((ext_vector_type(4))) float f32x4;

__device__ __forceinline__ short bf16_rne(float x){
  unsigned u = __builtin_bit_cast(unsigned, x);
  unsigned r = (u + 0x7FFFu + ((u >> 16) & 1u)) >> 16;
  return (short)r;
}
__device__ __forceinline__ float bf16_to_f(short h){
  unsigned u = ((unsigned)(unsigned short)h) << 16;
  return __builtin_bit_cast(float, u);
}
__device__ __forceinline__ float wave_reduce(float v){
  #pragma unroll
  for (int d = 1; d < 64; d <<= 1) v += __shfl_xor(v, d, 64);
  return v;
}
// swizzled fragment-major A granule index (16B granules); ks 0..7, mt 0..3
__device__ __forceinline__ int a_gran(int mt, int mrow, int ks, int kgrp){
  return (((((mt*8 + ks)*4 + kgrp)*2 + (mrow>>3)) << 3)
          | ((mrow & 7) ^ ((ks & 3) << 1) ^ (kgrp & 1)));
}
__device__ __forceinline__ float block_reduce_sum_256(float v, float* red){
  int t = threadIdx.x;
  red[t] = v; __syncthreads();
  #pragma unroll
  for (int s = 128; s > 0; s >>= 1){
    if (t < s) red[t] += red[t+s];
    __syncthreads();
  }
  float r = red[0];
  __syncthreads();
  return r;
}

// ---------------- bconv + fused init (block 0 zeroes accumulators) ----------------
__global__ __launch_bounds__(256) void bconv_kernel(const float* __restrict__ W1,
                                                    short* __restrict__ bth,
                                                    short* __restrict__ btl,
                                                    int* cnt_all, float* S, float* Se,
                                                    int* counters, float* loss, int* rcnt){
  const int i = blockIdx.x*256 + threadIdx.x;
  // fused init: first 16 blocks cover cnt_all[4096]; block 0 covers the scalars
  if (i < N_GR) cnt_all[i] = 0;
  if (i < DIM){ S[i] = 0.f; Se[i] = 0.f; }
  if (i < 2) counters[i] = 0;
  if (i == 0){ loss[0] = 0.f; rcnt[0] = 0; }
  const int k = i >> 9;
  const int j = i & 511;
  const float x = W1[i];
  const short h = bf16_rne(x);
  const short l = bf16_rne(x - bf16_to_f(h));
  const int nt = j >> 4, mrow = j & 15;
  const int ksg = k >> 5, kgrp = (k >> 3) & 3, kk = k & 7;
  const int lane = kgrp*16 + mrow;
  const size_t dst = (((size_t)(nt*8 + ksg)*64 + lane) << 3) + kk;
  bth[dst] = h;
  btl[dst] = l;
}

// ---------------- kernel A: manual-staged full-K 3-term MFMA, 2 blocks/CU ----------------
// 512 thr = 8 waves; 64 rows/block; K=256 resident; __launch_bounds__(512,4) pins
// total regs <=128 (64 AGPR acc + <=64 VGPR) -> 16 waves/CU -> cross-block overlap.
__global__ __launch_bounds__(512, 4) void mask_gemm(
    const float* __restrict__ hsub, const short* __restrict__ bth,
    const short* __restrict__ btl, const float* __restrict__ b1,
    const float* __restrict__ W2, const float* __restrict__ b2,
    const int* __restrict__ s2g, float* __restrict__ mask_out,
    int* __restrict__ cnt_all, int* __restrict__ rlist, int* __restrict__ rcnt)
{
  __shared__ short a_hi[16384];     // 32 KB swizzled fragment-major (64 rows x 256 k)
  __shared__ short a_lo[16384];     // 32 KB
  __shared__ float sred[512];       // 2 KB  -> 66 KB total (2x66=132 <= 160)
  const int tid = threadIdx.x;
  const int lane = tid & 63;
  const int q = tid >> 6;
  const int mrow = lane & 15;
  const int kgrp = lane >> 4;
  const int brow = blockIdx.x*MROWS;

  f32x4 acc[4][4];
  #pragma unroll
  for (int mt=0; mt<4; ++mt)
    #pragma unroll
    for (int nt=0; nt<4; ++nt) acc[mt][nt] = (f32x4){0.f,0.f,0.f,0.f};

  // ---- stage: two batches of 4 hoisted float4 loads (16 VGPR peak) ----
  const float* __restrict__ gbase = hsub + (size_t)brow*DIM;
  #pragma unroll
  for (int b = 0; b < 2; ++b){
    float4 g[4];
    #pragma unroll
    for (int i = 0; i < 4; ++i){
      const int idx = (b*4 + i)*512 + tid;       // float4 chunk 0..4095
      g[i] = *reinterpret_cast<const float4*>(gbase + (size_t)idx*4);
    }
    #pragma unroll
    for (int i = 0; i < 4; ++i){
      const int idx = (b*4 + i)*512 + tid;
      const int rr = idx >> 6;                   // row 0..63
      const int ch = idx & 63;                   // full-K chunk 0..63
      const float4 v = g[i];
      const short h0=bf16_rne(v.x), h1=bf16_rne(v.y), h2=bf16_rne(v.z), h3=bf16_rne(v.w);
      const short l0=bf16_rne(v.x-bf16_to_f(h0)), l1=bf16_rne(v.y-bf16_to_f(h1));
      const short l2=bf16_rne(v.z-bf16_to_f(h2)), l3=bf16_rne(v.w-bf16_to_f(h3));
      const int so = a_gran(rr>>4, rr&15, ch>>3, (ch>>1)&3)*8 + (ch&1)*4;
      *reinterpret_cast<short4*>(&a_hi[so]) = make_short4(h0,h1,h2,h3);
      *reinterpret_cast<short4*>(&a_lo[so]) = make_short4(l0,l1,l2,l3);
    }
  }
  __syncthreads();

#define LOADB(KSG)                                                            \
  { _Pragma("unroll")                                                         \
    for (int nt=0; nt<4; ++nt){                                               \
      const size_t bo = (((size_t)((q*4+nt)*8 + (KSG))*64 + lane) << 3);      \
      Bh[nt] = *reinterpret_cast<const short8*>(bth + bo);                    \
      Bl[nt] = *reinterpret_cast<const short8*>(btl + bo);                    \
    } }

  short8 Bh[4], Bl[4];
  #pragma unroll
  for (int ks = 0; ks < 8; ++ks){
    LOADB(ks);
    #pragma unroll
    for (int m = 0; m < 4; ++m){
      const int so = a_gran(m, mrow, ks, kgrp)*8;
      const short8 Ah = *reinterpret_cast<const short8*>(&a_hi[so]);
      const short8 Al = *reinterpret_cast<const short8*>(&a_lo[so]);
      #pragma unroll
      for (int nt=0; nt<4; ++nt){
        acc[m][nt] = __builtin_amdgcn_mfma_f32_16x16x32_bf16(Ah, Bh[nt], acc[m][nt], 0,0,0);
        acc[m][nt] = __builtin_amdgcn_mfma_f32_16x16x32_bf16(Ah, Bl[nt], acc[m][nt], 0,0,0);
        acc[m][nt] = __builtin_amdgcn_mfma_f32_16x16x32_bf16(Al, Bh[nt], acc[m][nt], 0,0,0);
      }
    }
  }

  // ---- epilogue: bias + ReLU + W2 dot; reduce 16 n-lanes; combine 8 waves ----
  float w2v[4], b1v[4];
  #pragma unroll
  for (int nt=0; nt<4; ++nt){
    const int n = q*64 + nt*16 + mrow;    // C: col = lane&15
    w2v[nt] = W2[n]; b1v[nt] = b1[n];
  }
  #pragma unroll
  for (int mt=0; mt<4; ++mt){
    #pragma unroll
    for (int r=0; r<4; ++r){
      float s = 0.f;
      #pragma unroll
      for (int nt=0; nt<4; ++nt)
        s += fmaxf(acc[mt][nt][r] + b1v[nt], 0.f) * w2v[nt];
      s += __shfl_xor(s, 1, 64);
      s += __shfl_xor(s, 2, 64);
      s += __shfl_xor(s, 4, 64);
      s += __shfl_xor(s, 8, 64);
      if (mrow == 0)
        sred[q*64 + mt*16 + kgrp*4 + r] = s;   // C: row = (lane>>4)*4 + reg
    }
  }
  __syncthreads();
  if (tid < MROWS){
    const int rr = brow + tid;
    float tot = b2[0];
    #pragma unroll
    for (int w = 0; w < 8; ++w) tot += sred[w*64 + tid];
    const float m = 1.f / (1.f + expf(-tot));
    mask_out[rr] = m;
    atomicAdd(&cnt_all[s2g[rr]], 1);
    if (fabsf(m - 0.4f) < RMARG || fabsf(m - 0.3f) < RMARG){
      const int p = atomicAdd(rcnt, 1);
      if (p < RCAP) rlist[p] = rr;
    }
  }
#undef LOADB
}

// ---------------- refine: exact fp32 logit for borderline rows ----------------
__global__ __launch_bounds__(256) void refine_kernel(
    const float* __restrict__ hsub, const float* __restrict__ W1,
    const float* __restrict__ b1, const float* __restrict__ W2,
    const float* __restrict__ b2, const int* __restrict__ rlist,
    const int* __restrict__ rcnt, float* __restrict__ mask_out)
{
  __shared__ float arow[256];
  __shared__ float red[256];
  const int n = min(rcnt[0], RCAP);
  const int t = threadIdx.x;
  for (int it = blockIdx.x; it < n; it += gridDim.x){
    const int row = rlist[it];
    arow[t] = hsub[(size_t)row*DIM + t];
    __syncthreads();
    float s = 0.f;
    #pragma unroll
    for (int jj = 0; jj < 2; ++jj){
      const int j = jj*256 + t;
      float y = b1[j];
      for (int k = 0; k < 256; ++k)
        y = fmaf(arow[k], W1[(size_t)k*512 + j], y);
      s += fmaxf(y, 0.f) * W2[j];
    }
    const float tot = block_reduce_sum_256(s, red);
    if (t == 0) mask_out[row] = 1.f / (1.f + expf(-(tot + b2[0])));
    __syncthreads();
  }
}

// ---------------- CSR build: scan + fill ----------------
__global__ __launch_bounds__(1024) void scan_kernel(const int* __restrict__ cnt,
                                                    int* __restrict__ offs,
                                                    int* __restrict__ cursor){
  __shared__ int buf[1024];
  const int t = threadIdx.x;
  const int c0 = cnt[t*4], c1 = cnt[t*4+1], c2 = cnt[t*4+2], c3 = cnt[t*4+3];
  const int s = c0+c1+c2+c3;
  buf[t] = s; __syncthreads();
  for (int d = 1; d < 1024; d <<= 1){
    int v = (t >= d) ? buf[t-d] : 0;
    __syncthreads();
    buf[t] += v;
    __syncthreads();
  }
  const int excl = buf[t] - s;
  const int o0 = excl, o1 = excl+c0, o2 = o1+c1, o3 = o2+c2;
  offs[t*4]=o0; offs[t*4+1]=o1; offs[t*4+2]=o2; offs[t*4+3]=o3;
  cursor[t*4]=o0; cursor[t*4+1]=o1; cursor[t*4+2]=o2; cursor[t*4+3]=o3;
  if (t == 1023) offs[4096] = buf[1023];
}

__global__ void fill_kernel(const int* __restrict__ s2g, int* __restrict__ cursor,
                            int* __restrict__ list){
  const int i = blockIdx.x*blockDim.x + threadIdx.x;
  if (i < N_SUB){
    const int g = s2g[i];
    const int p = atomicAdd(&cursor[g], 1);
    list[p] = i;
  }
}

// ---------------- kernel C: per-graph masked means (batched gather) ----------------
__global__ __launch_bounds__(256) void graph_means(
    const float* __restrict__ hsub, const float* __restrict__ mask,
    const int* __restrict__ list, const int* __restrict__ offs,
    const float* __restrict__ hgraph, const float* __restrict__ Wc,
    const float* __restrict__ bc, unsigned short* __restrict__ hatAb,
    float* __restrict__ S, float* __restrict__ Se,
    int* __restrict__ nzflags, int* __restrict__ counters,
    float* __restrict__ out)
{
  __shared__ int   sidx[256];
  __shared__ unsigned char sflag[256];
  __shared__ float wr4[4][4];
  __shared__ float wrc[TCLS][4];
  const int g = blockIdx.x;
  const int t = threadIdx.x;
  const int w = t >> 6, lane = t & 63;
  const int start = offs[g], end = offs[g+1];
  const int cnt = end - start;
  float sv = 0.f, sev = 0.f;
  int cv = 0, ce = 0;
  for (int base = 0; base < cnt; base += 256){
    const int nb = min(256, cnt - base);
    __syncthreads();
    if (t < nb){
      const int i = list[start + base + t];
      sidx[t] = i;
      const float m = mask[i];
      sflag[t] = (m > 0.4f) ? 1 : ((m <= 0.3f) ? 2 : 0);
    }
    __syncthreads();
    for (int p = 0; p < nb; p += 4){
      const int lim = nb - p;
      // register-prefetch indices+flags (issue LDS reads together, then VMEM together)
      const int i0 = sidx[p];
      const int i1 = (lim > 1) ? sidx[p+1] : i0;
      const int i2 = (lim > 2) ? sidx[p+2] : i0;
      const int i3 = (lim > 3) ? sidx[p+3] : i0;
      const int f0 = sflag[p];
      const int f1 = (lim > 1) ? sflag[p+1] : 0;
      const int f2 = (lim > 2) ? sflag[p+2] : 0;
      const int f3 = (lim > 3) ? sflag[p+3] : 0;
      const float v0 = hsub[(size_t)i0*DIM + t];
      const float v1 = hsub[(size_t)i1*DIM + t];
      const float v2 = hsub[(size_t)i2*DIM + t];
      const float v3 = hsub[(size_t)i3*DIM + t];
      if (f0==1){ sv+=v0; cv++; } else if (f0==2){ sev+=v0; ce++; }
      if (f1==1){ sv+=v1; cv++; } else if (f1==2){ sev+=v1; ce++; }
      if (f2==1){ sv+=v2; cv++; } else if (f2==2){ sev+=v2; ce++; }
      if (f3==1){ sv+=v3; cv++; } else if (f3==2){ sev+=v3; ce++; }
    }
  }
  __syncthreads();
  const float aligned = sv  / fmaxf((float)cv, 1.f);
  const float envv    = sev / fmaxf((float)ce, 1.f);
  float r0 = wave_reduce(aligned*aligned);
  float r1 = wave_reduce(envv*envv);
  float r2 = wave_reduce(aligned != 0.f ? 1.f : 0.f);
  float r3 = wave_reduce(envv    != 0.f ? 1.f : 0.f);
  if (lane == 0){ wr4[w][0]=r0; wr4[w][1]=r1; wr4[w][2]=r2; wr4[w][3]=r3; }
  __syncthreads();
  const float an2  = wr4[0][0]+wr4[1][0]+wr4[2][0]+wr4[3][0];
  const float en2  = wr4[0][1]+wr4[1][1]+wr4[2][1]+wr4[3][1];
  const float nzpf = wr4[0][2]+wr4[1][2]+wr4[2][2]+wr4[3][2];
  const float nzef = wr4[0][3]+wr4[1][3]+wr4[2][3]+wr4[3][3];
  const bool nzp = nzpf > 0.f, nze = nzef > 0.f;
  const float an = fmaxf(sqrtf(an2), 1e-8f);
  const float en = fmaxf(sqrtf(en2), 1e-8f);
  const float ha = aligned / an;
  hatAb[(size_t)g*DIM + t] = (unsigned short)bf16_rne(ha);
  atomicAdd(&S[t], ha);
  if (nze) atomicAdd(&Se[t], envv / en);
  if (t == 0){
    nzflags[g] = nzp ? 1 : 0;
    if (nzp) atomicAdd(&counters[0], 1);
    if (nze) atomicAdd(&counters[1], 1);
  }
  const float hg = hgraph[(size_t)g*DIM + t];
  #pragma unroll
  for (int c = 0; c < TCLS; ++c){
    float part = hg*Wc[t*TCLS+c] + aligned*Wc[(DIM+t)*TCLS+c];
    part = wave_reduce(part);
    if (lane == 0) wrc[c][w] = part;
  }
  __syncthreads();
  if (t < TCLS)
    out[g*TCLS + t] = wrc[t][0]+wrc[t][1]+wrc[t][2]+wrc[t][3] + bc[t];
}

// ---------------- kernel D: contrastive loss via rank-1 identity ----------------
__global__ __launch_bounds__(256) void loss_kernel(
    const unsigned short* __restrict__ hatAb, const float* __restrict__ S,
    const float* __restrict__ Se, const int* __restrict__ nzflags,
    const int* __restrict__ counters, float* __restrict__ loss)
{
  __shared__ float wr[4][2];
  const int g = blockIdx.x, t = threadIdx.x;
  const int w = t >> 6, lane = t & 63;
  const float ha = bf16_to_f((short)hatAb[(size_t)g*DIM + t]);
  float p0 = wave_reduce(ha*S[t]);
  float p1 = wave_reduce(ha*Se[t]);
  if (lane == 0){ wr[w][0] = p0; wr[w][1] = p1; }
  __syncthreads();
  if (t == 0){
    const float dS  = wr[0][0]+wr[1][0]+wr[2][0]+wr[3][0];
    const float dSe = wr[0][1]+wr[1][1]+wr[2][1]+wr[3][1];
    const int nzp_cnt = counters[0];
    const int nenv = counters[1];
    const float pos_num = fmaxf((float)(nzp_cnt - 1), 1.f);
    const float positive = (4096.f - dS) / pos_num;
    const float negative = ((float)nenv - dSe) / fmaxf((float)nenv, 1.f);
    float contrib = fmaxf(positive - negative + 1.f, 0.f);
    contrib *= (nzflags[g] ? 1.f : 0.f) * ((nenv > 0) ? 1.f : 0.f);
    atomicAdd(loss, contrib * (1.f/4096.f));
  }
}

// ---------------- launch ----------------
extern "C" void kernel_launch(void* const* d_in, const int* in_sizes, int n_in,
                              void* d_out, int out_size, void* d_ws, size_t ws_size,
                              hipStream_t stream) {
  const float* h_graph = (const float*)d_in[0];
  const float* h_sub   = (const float*)d_in[1];
  const float* W1      = (const float*)d_in[2];
  const float* b1      = (const float*)d_in[3];
  const float* W2      = (const float*)d_in[4];
  const float* b2      = (const float*)d_in[5];
  const float* Wc      = (const float*)d_in[6];
  const float* bc      = (const float*)d_in[7];
  const int*   s2g     = (const int*)d_in[8];

  float* out  = (float*)d_out;          // [4096,10]
  float* loss = out + N_GR*TCLS;        // scalar
  float* mask = loss + 1;               // [200000]

  // workspace layout — ~3.5 MB (proven-safe)
  char* ws = (char*)d_ws;
  short* bth    = (short*)ws;                          // 256 KB
  short* btl    = bth + HID*DIM;                       // 256 KB
  unsigned short* hatAb = (unsigned short*)(btl + HID*DIM);  // 2 MB
  int* cnt_all  = (int*)(hatAb + (size_t)N_GR*DIM);    // 4096
  int* offs     = cnt_all + N_GR;                      // 4097
  int* cursor   = offs + N_GR + 1;                     // 4096
  int* list     = cursor + N_GR;                       // 200000
  int* nzflags  = list + N_SUB;                        // 4096
  int* counters = nzflags + N_GR;                      // 2
  int* rcnt     = counters + 2;                        // 1
  int* rlist    = rcnt + 1;                            // 16384
  float* S      = (float*)(rlist + RCAP);              // 256
  float* Se     = S + DIM;                             // 256

  hipLaunchKernelGGL(bconv_kernel, dim3(HID*DIM/256), dim3(256), 0, stream,
                     W1, bth, btl, cnt_all, S, Se, counters, loss, rcnt);
  hipLaunchKernelGGL(mask_gemm, dim3(N_SUB/MROWS), dim3(512), 0, stream,
                     h_sub, bth, btl, b1, W2, b2, s2g, mask, cnt_all, rlist, rcnt);
  hipLaunchKernelGGL(refine_kernel, dim3(384), dim3(256), 0, stream,
                     h_sub, W1, b1, W2, b2, rlist, rcnt, mask);
  hipLaunchKernelGGL(scan_kernel, dim3(1), dim3(1024), 0, stream,
                     cnt_all, offs, cursor);
  hipLaunchKernelGGL(fill_kernel, dim3((N_SUB+255)/256), dim3(256), 0, stream,
                     s2g, cursor, list);
  hipLaunchKernelGGL(graph_means, dim3(N_GR), dim3(256), 0, stream,
                     h_sub, mask, list, offs, h_graph, Wc, bc,
                     hatAb, S, Se, nzflags, counters, out);
  hipLaunchKernelGGL(loss_kernel, dim3(N_GR), dim3(256), 0, stream,
                     hatAb, S, Se, nzflags, counters, loss);
}

// Round 19
// 449.800 us; speedup vs baseline: 8.8387x; 1.0148x over previous
//
#include <hip/hip_runtime.h>

#define N_SUB 200000
#define N_GR  4096
#define DIM   256
#define HID   512
#define TCLS  10
#define MROWS 64             // 3125 * 64 = 200000 exactly (no tail)
#define RCAP  16384
#define RMARG 1e-3f

typedef __attribute__((ext_vector_type(8))) short short8;
typedef __attribute__((ext_vector_type(4))) float f32x4;

__device__ __forceinline__ short bf16_rne(float x){
  unsigned u = __builtin_bit_cast(unsigned, x);
  unsigned r = (u + 0x7FFFu + ((u >> 16) & 1u)) >> 16;
  return (short)r;
}
__device__ __forceinline__ float bf16_to_f(short h){
  unsigned u = ((unsigned)(unsigned short)h) << 16;
  return __builtin_bit_cast(float, u);
}
__device__ __forceinline__ float wave_reduce(float v){
  #pragma unroll
  for (int d = 1; d < 64; d <<= 1) v += __shfl_xor(v, d, 64);
  return v;
}
// swizzled fragment-major A granule index (16B granules); ks 0..7, mt 0..3
__device__ __forceinline__ int a_gran(int mt, int mrow, int ks, int kgrp){
  return (((((mt*8 + ks)*4 + kgrp)*2 + (mrow>>3)) << 3)
          | ((mrow & 7) ^ ((ks & 3) << 1) ^ (kgrp & 1)));
}

// ---------------- bconv + fused init (block 0 zeroes accumulators) ----------------
__global__ __launch_bounds__(256) void bconv_kernel(const float* __restrict__ W1,
                                                    short* __restrict__ bth,
                                                    short* __restrict__ btl,
                                                    int* cnt_all, float* S, float* Se,
                                                    int* counters, float* loss, int* rcnt){
  const int i = blockIdx.x*256 + threadIdx.x;
  // fused init: first 16 blocks cover cnt_all[4096]; block 0 covers the scalars
  if (i < N_GR) cnt_all[i] = 0;
  if (i < DIM){ S[i] = 0.f; Se[i] = 0.f; }
  if (i < 2) counters[i] = 0;
  if (i == 0){ loss[0] = 0.f; rcnt[0] = 0; }
  const int k = i >> 9;
  const int j = i & 511;
  const float x = W1[i];
  const short h = bf16_rne(x);
  const short l = bf16_rne(x - bf16_to_f(h));
  const int nt = j >> 4, mrow = j & 15;
  const int ksg = k >> 5, kgrp = (k >> 3) & 3, kk = k & 7;
  const int lane = kgrp*16 + mrow;
  const size_t dst = (((size_t)(nt*8 + ksg)*64 + lane) << 3) + kk;
  bth[dst] = h;
  btl[dst] = l;
}

// ---------------- kernel A: manual-staged full-K 3-term MFMA, 2 blocks/CU ----------------
// 512 thr = 8 waves; 64 rows/block; K=256 resident; __launch_bounds__(512,4) pins
// total regs <=128 (64 AGPR acc + <=64 VGPR) -> 16 waves/CU -> cross-block overlap.
__global__ __launch_bounds__(512, 4) void mask_gemm(
    const float* __restrict__ hsub, const short* __restrict__ bth,
    const short* __restrict__ btl, const float* __restrict__ b1,
    const float* __restrict__ W2, const float* __restrict__ b2,
    const int* __restrict__ s2g, float* __restrict__ mask_out,
    int* __restrict__ cnt_all, int* __restrict__ rlist, int* __restrict__ rcnt)
{
  __shared__ short a_hi[16384];     // 32 KB swizzled fragment-major (64 rows x 256 k)
  __shared__ short a_lo[16384];     // 32 KB
  __shared__ float sred[512];       // 2 KB  -> 66 KB total (2x66=132 <= 160)
  const int tid = threadIdx.x;
  const int lane = tid & 63;
  const int q = tid >> 6;
  const int mrow = lane & 15;
  const int kgrp = lane >> 4;
  const int brow = blockIdx.x*MROWS;

  f32x4 acc[4][4];
  #pragma unroll
  for (int mt=0; mt<4; ++mt)
    #pragma unroll
    for (int nt=0; nt<4; ++nt) acc[mt][nt] = (f32x4){0.f,0.f,0.f,0.f};

  // ---- stage: two batches of 4 hoisted float4 loads (16 VGPR peak) ----
  const float* __restrict__ gbase = hsub + (size_t)brow*DIM;
  #pragma unroll
  for (int b = 0; b < 2; ++b){
    float4 g[4];
    #pragma unroll
    for (int i = 0; i < 4; ++i){
      const int idx = (b*4 + i)*512 + tid;       // float4 chunk 0..4095
      g[i] = *reinterpret_cast<const float4*>(gbase + (size_t)idx*4);
    }
    #pragma unroll
    for (int i = 0; i < 4; ++i){
      const int idx = (b*4 + i)*512 + tid;
      const int rr = idx >> 6;                   // row 0..63
      const int ch = idx & 63;                   // full-K chunk 0..63
      const float4 v = g[i];
      const short h0=bf16_rne(v.x), h1=bf16_rne(v.y), h2=bf16_rne(v.z), h3=bf16_rne(v.w);
      const short l0=bf16_rne(v.x-bf16_to_f(h0)), l1=bf16_rne(v.y-bf16_to_f(h1));
      const short l2=bf16_rne(v.z-bf16_to_f(h2)), l3=bf16_rne(v.w-bf16_to_f(h3));
      const int so = a_gran(rr>>4, rr&15, ch>>3, (ch>>1)&3)*8 + (ch&1)*4;
      *reinterpret_cast<short4*>(&a_hi[so]) = make_short4(h0,h1,h2,h3);
      *reinterpret_cast<short4*>(&a_lo[so]) = make_short4(l0,l1,l2,l3);
    }
  }
  __syncthreads();

#define LOADB(KSG)                                                            \
  { _Pragma("unroll")                                                         \
    for (int nt=0; nt<4; ++nt){                                               \
      const size_t bo = (((size_t)((q*4+nt)*8 + (KSG))*64 + lane) << 3);      \
      Bh[nt] = *reinterpret_cast<const short8*>(bth + bo);                    \
      Bl[nt] = *reinterpret_cast<const short8*>(btl + bo);                    \
    } }

  short8 Bh[4], Bl[4];
  #pragma unroll
  for (int ks = 0; ks < 8; ++ks){
    LOADB(ks);
    #pragma unroll
    for (int m = 0; m < 4; ++m){
      const int so = a_gran(m, mrow, ks, kgrp)*8;
      const short8 Ah = *reinterpret_cast<const short8*>(&a_hi[so]);
      const short8 Al = *reinterpret_cast<const short8*>(&a_lo[so]);
      #pragma unroll
      for (int nt=0; nt<4; ++nt){
        acc[m][nt] = __builtin_amdgcn_mfma_f32_16x16x32_bf16(Ah, Bh[nt], acc[m][nt], 0,0,0);
        acc[m][nt] = __builtin_amdgcn_mfma_f32_16x16x32_bf16(Ah, Bl[nt], acc[m][nt], 0,0,0);
        acc[m][nt] = __builtin_amdgcn_mfma_f32_16x16x32_bf16(Al, Bh[nt], acc[m][nt], 0,0,0);
      }
    }
  }

  // ---- epilogue: bias + ReLU + W2 dot; reduce 16 n-lanes; combine 8 waves ----
  float w2v[4], b1v[4];
  #pragma unroll
  for (int nt=0; nt<4; ++nt){
    const int n = q*64 + nt*16 + mrow;    // C: col = lane&15
    w2v[nt] = W2[n]; b1v[nt] = b1[n];
  }
  #pragma unroll
  for (int mt=0; mt<4; ++mt){
    #pragma unroll
    for (int r=0; r<4; ++r){
      float s = 0.f;
      #pragma unroll
      for (int nt=0; nt<4; ++nt)
        s += fmaxf(acc[mt][nt][r] + b1v[nt], 0.f) * w2v[nt];
      s += __shfl_xor(s, 1, 64);
      s += __shfl_xor(s, 2, 64);
      s += __shfl_xor(s, 4, 64);
      s += __shfl_xor(s, 8, 64);
      if (mrow == 0)
        sred[q*64 + mt*16 + kgrp*4 + r] = s;   // C: row = (lane>>4)*4 + reg
    }
  }
  __syncthreads();
  if (tid < MROWS){
    const int rr = brow + tid;
    float tot = b2[0];
    #pragma unroll
    for (int w = 0; w < 8; ++w) tot += sred[w*64 + tid];
    const float m = 1.f / (1.f + expf(-tot));
    mask_out[rr] = m;
    atomicAdd(&cnt_all[s2g[rr]], 1);
    if (fabsf(m - 0.4f) < RMARG || fabsf(m - 0.3f) < RMARG){
      const int p = atomicAdd(rcnt, 1);
      if (p < RCAP) rlist[p] = rr;
    }
  }
#undef LOADB
}

// ---------------- refine: exact fp32 logit, MLP-parallel (one j per thread) ----------------
// 512 threads = all hidden units; 4 independent k-accumulators + unroll 8 -> ~32
// loads in flight (round-18 diagnosis: rolled k-loop was latency-serial, ~250us wall).
__global__ __launch_bounds__(512) void refine_kernel(
    const float* __restrict__ hsub, const float* __restrict__ W1,
    const float* __restrict__ b1, const float* __restrict__ W2,
    const float* __restrict__ b2, const int* __restrict__ rlist,
    const int* __restrict__ rcnt, float* __restrict__ mask_out)
{
  __shared__ float arow[256];
  __shared__ float red[512];
  const int n = min(rcnt[0], RCAP);
  const int t = threadIdx.x;            // j = t, 0..511
  for (int it = blockIdx.x; it < n; it += gridDim.x){
    const int row = rlist[it];
    if (t < 256) arow[t] = hsub[(size_t)row*DIM + t];
    __syncthreads();
    float y0 = b1[t], y1 = 0.f, y2 = 0.f, y3 = 0.f;
    #pragma unroll 8
    for (int k = 0; k < 64; ++k){
      y0 = fmaf(arow[k],     W1[(size_t)k*512 + t],         y0);
      y1 = fmaf(arow[k+64],  W1[(size_t)(k+64)*512 + t],    y1);
      y2 = fmaf(arow[k+128], W1[(size_t)(k+128)*512 + t],   y2);
      y3 = fmaf(arow[k+192], W1[(size_t)(k+192)*512 + t],   y3);
    }
    const float y = (y0 + y1) + (y2 + y3);
    red[t] = fmaxf(y, 0.f) * W2[t];
    __syncthreads();
    #pragma unroll
    for (int off = 256; off > 0; off >>= 1){
      if (t < off) red[t] += red[t+off];
      __syncthreads();
    }
    if (t == 0) mask_out[row] = 1.f / (1.f + expf(-(red[0] + b2[0])));
    __syncthreads();
  }
}

// ---------------- CSR build: scan + fill ----------------
__global__ __launch_bounds__(1024) void scan_kernel(const int* __restrict__ cnt,
                                                    int* __restrict__ offs,
                                                    int* __restrict__ cursor){
  __shared__ int buf[1024];
  const int t = threadIdx.x;
  const int c0 = cnt[t*4], c1 = cnt[t*4+1], c2 = cnt[t*4+2], c3 = cnt[t*4+3];
  const int s = c0+c1+c2+c3;
  buf[t] = s; __syncthreads();
  for (int d = 1; d < 1024; d <<= 1){
    int v = (t >= d) ? buf[t-d] : 0;
    __syncthreads();
    buf[t] += v;
    __syncthreads();
  }
  const int excl = buf[t] - s;
  const int o0 = excl, o1 = excl+c0, o2 = o1+c1, o3 = o2+c2;
  offs[t*4]=o0; offs[t*4+1]=o1; offs[t*4+2]=o2; offs[t*4+3]=o3;
  cursor[t*4]=o0; cursor[t*4+1]=o1; cursor[t*4+2]=o2; cursor[t*4+3]=o3;
  if (t == 1023) offs[4096] = buf[1023];
}

__global__ void fill_kernel(const int* __restrict__ s2g, int* __restrict__ cursor,
                            int* __restrict__ list){
  const int i = blockIdx.x*blockDim.x + threadIdx.x;
  if (i < N_SUB){
    const int g = s2g[i];
    const int p = atomicAdd(&cursor[g], 1);
    list[p] = i;
  }
}

// ---------------- kernel C: per-graph masked means (batched gather) ----------------
__global__ __launch_bounds__(256) void graph_means(
    const float* __restrict__ hsub, const float* __restrict__ mask,
    const int* __restrict__ list, const int* __restrict__ offs,
    const float* __restrict__ hgraph, const float* __restrict__ Wc,
    const float* __restrict__ bc, unsigned short* __restrict__ hatAb,
    float* __restrict__ S, float* __restrict__ Se,
    int* __restrict__ nzflags, int* __restrict__ counters,
    float* __restrict__ out)
{
  __shared__ int   sidx[256];
  __shared__ unsigned char sflag[256];
  __shared__ float wr4[4][4];
  __shared__ float wrc[TCLS][4];
  const int g = blockIdx.x;
  const int t = threadIdx.x;
  const int w = t >> 6, lane = t & 63;
  const int start = offs[g], end = offs[g+1];
  const int cnt = end - start;
  float sv = 0.f, sev = 0.f;
  int cv = 0, ce = 0;
  for (int base = 0; base < cnt; base += 256){
    const int nb = min(256, cnt - base);
    __syncthreads();
    if (t < nb){
      const int i = list[start + base + t];
      sidx[t] = i;
      const float m = mask[i];
      sflag[t] = (m > 0.4f) ? 1 : ((m <= 0.3f) ? 2 : 0);
    }
    __syncthreads();
    for (int p = 0; p < nb; p += 4){
      const int lim = nb - p;
      // register-prefetch indices+flags (issue LDS reads together, then VMEM together)
      const int i0 = sidx[p];
      const int i1 = (lim > 1) ? sidx[p+1] : i0;
      const int i2 = (lim > 2) ? sidx[p+2] : i0;
      const int i3 = (lim > 3) ? sidx[p+3] : i0;
      const int f0 = sflag[p];
      const int f1 = (lim > 1) ? sflag[p+1] : 0;
      const int f2 = (lim > 2) ? sflag[p+2] : 0;
      const int f3 = (lim > 3) ? sflag[p+3] : 0;
      const float v0 = hsub[(size_t)i0*DIM + t];
      const float v1 = hsub[(size_t)i1*DIM + t];
      const float v2 = hsub[(size_t)i2*DIM + t];
      const float v3 = hsub[(size_t)i3*DIM + t];
      if (f0==1){ sv+=v0; cv++; } else if (f0==2){ sev+=v0; ce++; }
      if (f1==1){ sv+=v1; cv++; } else if (f1==2){ sev+=v1; ce++; }
      if (f2==1){ sv+=v2; cv++; } else if (f2==2){ sev+=v2; ce++; }
      if (f3==1){ sv+=v3; cv++; } else if (f3==2){ sev+=v3; ce++; }
    }
  }
  __syncthreads();
  const float aligned = sv  / fmaxf((float)cv, 1.f);
  const float envv    = sev / fmaxf((float)ce, 1.f);
  float r0 = wave_reduce(aligned*aligned);
  float r1 = wave_reduce(envv*envv);
  float r2 = wave_reduce(aligned != 0.f ? 1.f : 0.f);
  float r3 = wave_reduce(envv    != 0.f ? 1.f : 0.f);
  if (lane == 0){ wr4[w][0]=r0; wr4[w][1]=r1; wr4[w][2]=r2; wr4[w][3]=r3; }
  __syncthreads();
  const float an2  = wr4[0][0]+wr4[1][0]+wr4[2][0]+wr4[3][0];
  const float en2  = wr4[0][1]+wr4[1][1]+wr4[2][1]+wr4[3][1];
  const float nzpf = wr4[0][2]+wr4[1][2]+wr4[2][2]+wr4[3][2];
  const float nzef = wr4[0][3]+wr4[1][3]+wr4[2][3]+wr4[3][3];
  const bool nzp = nzpf > 0.f, nze = nzef > 0.f;
  const float an = fmaxf(sqrtf(an2), 1e-8f);
  const float en = fmaxf(sqrtf(en2), 1e-8f);
  const float ha = aligned / an;
  hatAb[(size_t)g*DIM + t] = (unsigned short)bf16_rne(ha);
  atomicAdd(&S[t], ha);
  if (nze) atomicAdd(&Se[t], envv / en);
  if (t == 0){
    nzflags[g] = nzp ? 1 : 0;
    if (nzp) atomicAdd(&counters[0], 1);
    if (nze) atomicAdd(&counters[1], 1);
  }
  const float hg = hgraph[(size_t)g*DIM + t];
  #pragma unroll
  for (int c = 0; c < TCLS; ++c){
    float part = hg*Wc[t*TCLS+c] + aligned*Wc[(DIM+t)*TCLS+c];
    part = wave_reduce(part);
    if (lane == 0) wrc[c][w] = part;
  }
  __syncthreads();
  if (t < TCLS)
    out[g*TCLS + t] = wrc[t][0]+wrc[t][1]+wrc[t][2]+wrc[t][3] + bc[t];
}

// ---------------- kernel D: contrastive loss via rank-1 identity ----------------
__global__ __launch_bounds__(256) void loss_kernel(
    const unsigned short* __restrict__ hatAb, const float* __restrict__ S,
    const float* __restrict__ Se, const int* __restrict__ nzflags,
    const int* __restrict__ counters, float* __restrict__ loss)
{
  __shared__ float wr[4][2];
  const int g = blockIdx.x, t = threadIdx.x;
  const int w = t >> 6, lane = t & 63;
  const float ha = bf16_to_f((short)hatAb[(size_t)g*DIM + t]);
  float p0 = wave_reduce(ha*S[t]);
  float p1 = wave_reduce(ha*Se[t]);
  if (lane == 0){ wr[w][0] = p0; wr[w][1] = p1; }
  __syncthreads();
  if (t == 0){
    const float dS  = wr[0][0]+wr[1][0]+wr[2][0]+wr[3][0];
    const float dSe = wr[0][1]+wr[1][1]+wr[2][1]+wr[3][1];
    const int nzp_cnt = counters[0];
    const int nenv = counters[1];
    const float pos_num = fmaxf((float)(nzp_cnt - 1), 1.f);
    const float positive = (4096.f - dS) / pos_num;
    const float negative = ((float)nenv - dSe) / fmaxf((float)nenv, 1.f);
    float contrib = fmaxf(positive - negative + 1.f, 0.f);
    contrib *= (nzflags[g] ? 1.f : 0.f) * ((nenv > 0) ? 1.f : 0.f);
    atomicAdd(loss, contrib * (1.f/4096.f));
  }
}

// ---------------- launch ----------------
extern "C" void kernel_launch(void* const* d_in, const int* in_sizes, int n_in,
                              void* d_out, int out_size, void* d_ws, size_t ws_size,
                              hipStream_t stream) {
  const float* h_graph = (const float*)d_in[0];
  const float* h_sub   = (const float*)d_in[1];
  const float* W1      = (const float*)d_in[2];
  const float* b1      = (const float*)d_in[3];
  const float* W2      = (const float*)d_in[4];
  const float* b2      = (const float*)d_in[5];
  const float* Wc      = (const float*)d_in[6];
  const float* bc      = (const float*)d_in[7];
  const int*   s2g     = (const int*)d_in[8];

  float* out  = (float*)d_out;          // [4096,10]
  float* loss = out + N_GR*TCLS;        // scalar
  float* mask = loss + 1;               // [200000]

  // workspace layout — ~3.5 MB (proven-safe)
  char* ws = (char*)d_ws;
  short* bth    = (short*)ws;                          // 256 KB
  short* btl    = bth + HID*DIM;                       // 256 KB
  unsigned short* hatAb = (unsigned short*)(btl + HID*DIM);  // 2 MB
  int* cnt_all  = (int*)(hatAb + (size_t)N_GR*DIM);    // 4096
  int* offs     = cnt_all + N_GR;                      // 4097
  int* cursor   = offs + N_GR + 1;                     // 4096
  int* list     = cursor + N_GR;                       // 200000
  int* nzflags  = list + N_SUB;                        // 4096
  int* counters = nzflags + N_GR;                      // 2
  int* rcnt     = counters + 2;                        // 1
  int* rlist    = rcnt + 1;                            // 16384
  float* S      = (float*)(rlist + RCAP);              // 256
  float* Se     = S + DIM;                             // 256

  hipLaunchKernelGGL(bconv_kernel, dim3(HID*DIM/256), dim3(256), 0, stream,
                     W1, bth, btl, cnt_all, S, Se, counters, loss, rcnt);
  hipLaunchKernelGGL(mask_gemm, dim3(N_SUB/MROWS), dim3(512), 0, stream,
                     h_sub, bth, btl, b1, W2, b2, s2g, mask, cnt_all, rlist, rcnt);
  hipLaunchKernelGGL(refine_kernel, dim3(384), dim3(512), 0, stream,
                     h_sub, W1, b1, W2, b2, rlist, rcnt, mask);
  hipLaunchKernelGGL(scan_kernel, dim3(1), dim3(1024), 0, stream,
                     cnt_all, offs, cursor);
  hipLaunchKernelGGL(fill_kernel, dim3((N_SUB+255)/256), dim3(256), 0, stream,
                     s2g, cursor, list);
  hipLaunchKernelGGL(graph_means, dim3(N_GR), dim3(256), 0, stream,
                     h_sub, mask, list, offs, h_graph, Wc, bc,
                     hatAb, S, Se, nzflags, counters, out);
  hipLaunchKernelGGL(loss_kernel, dim3(N_GR), dim3(256), 0, stream,
                     hatAb, S, Se, nzflags, counters, loss);
}

// Round 20
// 393.903 us; speedup vs baseline: 10.0930x; 1.1419x over previous
//
#include <hip/hip_runtime.h>

#define N_SUB 200000
#define N_GR  4096
#define DIM   256
#define HID   512
#define TCLS  10
#define MROWS 64             // 3125 * 64 = 200000 exactly (no tail)
#define RCAP  16384
#define RMARG 1e-3f
#define NREP  32             // S/Se replica count (atomic de-contention)

typedef __attribute__((ext_vector_type(8))) short short8;
typedef __attribute__((ext_vector_type(4))) float f32x4;

__device__ __forceinline__ short bf16_rne(float x){
  unsigned u = __builtin_bit_cast(unsigned, x);
  unsigned r = (u + 0x7FFFu + ((u >> 16) & 1u)) >> 16;
  return (short)r;
}
__device__ __forceinline__ float bf16_to_f(short h){
  unsigned u = ((unsigned)(unsigned short)h) << 16;
  return __builtin_bit_cast(float, u);
}
__device__ __forceinline__ float wave_reduce(float v){
  #pragma unroll
  for (int d = 1; d < 64; d <<= 1) v += __shfl_xor(v, d, 64);
  return v;
}
// swizzled fragment-major A granule index (16B granules); ks 0..7, mt 0..3
__device__ __forceinline__ int a_gran(int mt, int mrow, int ks, int kgrp){
  return (((((mt*8 + ks)*4 + kgrp)*2 + (mrow>>3)) << 3)
          | ((mrow & 7) ^ ((ks & 3) << 1) ^ (kgrp & 1)));
}

// ---------------- bconv + fused init ----------------
__global__ __launch_bounds__(256) void bconv_kernel(const float* __restrict__ W1,
                                                    short* __restrict__ bth,
                                                    short* __restrict__ btl,
                                                    int* cnt_all, float* S32, float* Se32,
                                                    int* counters, float* loss_p, int* rcnt){
  const int i = blockIdx.x*256 + threadIdx.x;
  if (i < N_GR) cnt_all[i] = 0;
  if (i < NREP*DIM){ S32[i] = 0.f; Se32[i] = 0.f; }
  if (i < 64) loss_p[i] = 0.f;
  if (i < 2) counters[i] = 0;
  if (i == 0) rcnt[0] = 0;
  const int k = i >> 9;
  const int j = i & 511;
  const float x = W1[i];
  const short h = bf16_rne(x);
  const short l = bf16_rne(x - bf16_to_f(h));
  const int nt = j >> 4, mrow = j & 15;
  const int ksg = k >> 5, kgrp = (k >> 3) & 3, kk = k & 7;
  const int lane = kgrp*16 + mrow;
  const size_t dst = (((size_t)(nt*8 + ksg)*64 + lane) << 3) + kk;
  bth[dst] = h;
  btl[dst] = l;
}

// ---------------- kernel A: manual-staged full-K 3-term MFMA, 2 blocks/CU ----------------
// nt-outer/m-inner inner loop: 32 A-regs + 8 B-regs live (was 48) -> fit 64 VGPR, no spill.
__global__ __launch_bounds__(512, 4) void mask_gemm(
    const float* __restrict__ hsub, const short* __restrict__ bth,
    const short* __restrict__ btl, const float* __restrict__ b1,
    const float* __restrict__ W2, const float* __restrict__ b2,
    const int* __restrict__ s2g, float* __restrict__ mask_out,
    int* __restrict__ cnt_all, int* __restrict__ rlist, int* __restrict__ rcnt)
{
  __shared__ short a_hi[16384];     // 32 KB swizzled fragment-major (64 rows x 256 k)
  __shared__ short a_lo[16384];     // 32 KB
  __shared__ float sred[512];       // 2 KB  -> 66 KB total (2x66=132 <= 160)
  const int tid = threadIdx.x;
  const int lane = tid & 63;
  const int q = tid >> 6;
  const int mrow = lane & 15;
  const int kgrp = lane >> 4;
  const int brow = blockIdx.x*MROWS;

  f32x4 acc[4][4];
  #pragma unroll
  for (int mt=0; mt<4; ++mt)
    #pragma unroll
    for (int nt=0; nt<4; ++nt) acc[mt][nt] = (f32x4){0.f,0.f,0.f,0.f};

  // ---- stage: two batches of 4 hoisted float4 loads (16 VGPR peak) ----
  const float* __restrict__ gbase = hsub + (size_t)brow*DIM;
  #pragma unroll
  for (int b = 0; b < 2; ++b){
    float4 g[4];
    #pragma unroll
    for (int i = 0; i < 4; ++i){
      const int idx = (b*4 + i)*512 + tid;       // float4 chunk 0..4095
      g[i] = *reinterpret_cast<const float4*>(gbase + (size_t)idx*4);
    }
    #pragma unroll
    for (int i = 0; i < 4; ++i){
      const int idx = (b*4 + i)*512 + tid;
      const int rr = idx >> 6;                   // row 0..63
      const int ch = idx & 63;                   // full-K chunk 0..63
      const float4 v = g[i];
      const short h0=bf16_rne(v.x), h1=bf16_rne(v.y), h2=bf16_rne(v.z), h3=bf16_rne(v.w);
      const short l0=bf16_rne(v.x-bf16_to_f(h0)), l1=bf16_rne(v.y-bf16_to_f(h1));
      const short l2=bf16_rne(v.z-bf16_to_f(h2)), l3=bf16_rne(v.w-bf16_to_f(h3));
      const int so = a_gran(rr>>4, rr&15, ch>>3, (ch>>1)&3)*8 + (ch&1)*4;
      *reinterpret_cast<short4*>(&a_hi[so]) = make_short4(h0,h1,h2,h3);
      *reinterpret_cast<short4*>(&a_lo[so]) = make_short4(l0,l1,l2,l3);
    }
  }
  __syncthreads();

  short8 Ah[4], Al[4];
  #pragma unroll
  for (int ks = 0; ks < 8; ++ks){
    #pragma unroll
    for (int m = 0; m < 4; ++m){
      const int so = a_gran(m, mrow, ks, kgrp)*8;
      Ah[m] = *reinterpret_cast<const short8*>(&a_hi[so]);
      Al[m] = *reinterpret_cast<const short8*>(&a_lo[so]);
    }
    #pragma unroll
    for (int nt = 0; nt < 4; ++nt){
      const size_t bo = (((size_t)((q*4+nt)*8 + ks)*64 + lane) << 3);
      const short8 Bh = *reinterpret_cast<const short8*>(bth + bo);
      const short8 Bl = *reinterpret_cast<const short8*>(btl + bo);
      #pragma unroll
      for (int m = 0; m < 4; ++m){
        acc[m][nt] = __builtin_amdgcn_mfma_f32_16x16x32_bf16(Ah[m], Bh, acc[m][nt], 0,0,0);
        acc[m][nt] = __builtin_amdgcn_mfma_f32_16x16x32_bf16(Ah[m], Bl, acc[m][nt], 0,0,0);
        acc[m][nt] = __builtin_amdgcn_mfma_f32_16x16x32_bf16(Al[m], Bh, acc[m][nt], 0,0,0);
      }
    }
  }

  // ---- epilogue: bias + ReLU + W2 dot; reduce 16 n-lanes; combine 8 waves ----
  float w2v[4], b1v[4];
  #pragma unroll
  for (int nt=0; nt<4; ++nt){
    const int n = q*64 + nt*16 + mrow;    // C: col = lane&15
    w2v[nt] = W2[n]; b1v[nt] = b1[n];
  }
  #pragma unroll
  for (int mt=0; mt<4; ++mt){
    #pragma unroll
    for (int r=0; r<4; ++r){
      float s = 0.f;
      #pragma unroll
      for (int nt=0; nt<4; ++nt)
        s += fmaxf(acc[mt][nt][r] + b1v[nt], 0.f) * w2v[nt];
      s += __shfl_xor(s, 1, 64);
      s += __shfl_xor(s, 2, 64);
      s += __shfl_xor(s, 4, 64);
      s += __shfl_xor(s, 8, 64);
      if (mrow == 0)
        sred[q*64 + mt*16 + kgrp*4 + r] = s;   // C: row = (lane>>4)*4 + reg
    }
  }
  __syncthreads();
  if (tid < MROWS){
    const int rr = brow + tid;
    float tot = b2[0];
    #pragma unroll
    for (int w = 0; w < 8; ++w) tot += sred[w*64 + tid];
    const float m = 1.f / (1.f + expf(-tot));
    mask_out[rr] = m;
    atomicAdd(&cnt_all[s2g[rr]], 1);
    if (fabsf(m - 0.4f) < RMARG || fabsf(m - 0.3f) < RMARG){
      const int p = atomicAdd(rcnt, 1);
      if (p < RCAP) rlist[p] = rr;
    }
  }
}

// ---------------- refine: exact fp32 logit, MLP-parallel ----------------
__global__ __launch_bounds__(512) void refine_kernel(
    const float* __restrict__ hsub, const float* __restrict__ W1,
    const float* __restrict__ b1, const float* __restrict__ W2,
    const float* __restrict__ b2, const int* __restrict__ rlist,
    const int* __restrict__ rcnt, float* __restrict__ mask_out)
{
  __shared__ float arow[256];
  __shared__ float red[512];
  const int n = min(rcnt[0], RCAP);
  const int t = threadIdx.x;            // j = t, 0..511
  for (int it = blockIdx.x; it < n; it += gridDim.x){
    const int row = rlist[it];
    if (t < 256) arow[t] = hsub[(size_t)row*DIM + t];
    __syncthreads();
    float y0 = b1[t], y1 = 0.f, y2 = 0.f, y3 = 0.f;
    #pragma unroll 8
    for (int k = 0; k < 64; ++k){
      y0 = fmaf(arow[k],     W1[(size_t)k*512 + t],         y0);
      y1 = fmaf(arow[k+64],  W1[(size_t)(k+64)*512 + t],    y1);
      y2 = fmaf(arow[k+128], W1[(size_t)(k+128)*512 + t],   y2);
      y3 = fmaf(arow[k+192], W1[(size_t)(k+192)*512 + t],   y3);
    }
    const float y = (y0 + y1) + (y2 + y3);
    red[t] = fmaxf(y, 0.f) * W2[t];
    __syncthreads();
    #pragma unroll
    for (int off = 256; off > 0; off >>= 1){
      if (t < off) red[t] += red[t+off];
      __syncthreads();
    }
    if (t == 0) mask_out[row] = 1.f / (1.f + expf(-(red[0] + b2[0])));
    __syncthreads();
  }
}

// ---------------- CSR build: scan + fill ----------------
__global__ __launch_bounds__(1024) void scan_kernel(const int* __restrict__ cnt,
                                                    int* __restrict__ offs,
                                                    int* __restrict__ cursor){
  __shared__ int buf[1024];
  const int t = threadIdx.x;
  const int c0 = cnt[t*4], c1 = cnt[t*4+1], c2 = cnt[t*4+2], c3 = cnt[t*4+3];
  const int s = c0+c1+c2+c3;
  buf[t] = s; __syncthreads();
  for (int d = 1; d < 1024; d <<= 1){
    int v = (t >= d) ? buf[t-d] : 0;
    __syncthreads();
    buf[t] += v;
    __syncthreads();
  }
  const int excl = buf[t] - s;
  const int o0 = excl, o1 = excl+c0, o2 = o1+c1, o3 = o2+c2;
  offs[t*4]=o0; offs[t*4+1]=o1; offs[t*4+2]=o2; offs[t*4+3]=o3;
  cursor[t*4]=o0; cursor[t*4+1]=o1; cursor[t*4+2]=o2; cursor[t*4+3]=o3;
  if (t == 1023) offs[4096] = buf[1023];
}

__global__ void fill_kernel(const int* __restrict__ s2g, int* __restrict__ cursor,
                            int* __restrict__ list){
  const int i = blockIdx.x*blockDim.x + threadIdx.x;
  if (i < N_SUB){
    const int g = s2g[i];
    const int p = atomicAdd(&cursor[g], 1);
    list[p] = i;
  }
}

// ---------------- kernel C: per-graph masked means (replica-spread atomics) ----------------
__global__ __launch_bounds__(256) void graph_means(
    const float* __restrict__ hsub, const float* __restrict__ mask,
    const int* __restrict__ list, const int* __restrict__ offs,
    const float* __restrict__ hgraph, const float* __restrict__ Wc,
    const float* __restrict__ bc, unsigned short* __restrict__ hatAb,
    float* __restrict__ S32, float* __restrict__ Se32,
    int* __restrict__ nzflags, int* __restrict__ counters,
    float* __restrict__ out)
{
  __shared__ int   sidx[256];
  __shared__ unsigned char sflag[256];
  __shared__ float wr4[4][4];
  __shared__ float wrc[TCLS][4];
  const int g = blockIdx.x;
  const int t = threadIdx.x;
  const int w = t >> 6, lane = t & 63;
  const int start = offs[g], end = offs[g+1];
  const int cnt = end - start;
  float sv = 0.f, sev = 0.f;
  int cv = 0, ce = 0;
  for (int base = 0; base < cnt; base += 256){
    const int nb = min(256, cnt - base);
    __syncthreads();
    if (t < nb){
      const int i = list[start + base + t];
      sidx[t] = i;
      const float m = mask[i];
      sflag[t] = (m > 0.4f) ? 1 : ((m <= 0.3f) ? 2 : 0);
    }
    __syncthreads();
    for (int p = 0; p < nb; p += 4){
      const int lim = nb - p;
      const int i0 = sidx[p];
      const int i1 = (lim > 1) ? sidx[p+1] : i0;
      const int i2 = (lim > 2) ? sidx[p+2] : i0;
      const int i3 = (lim > 3) ? sidx[p+3] : i0;
      const int f0 = sflag[p];
      const int f1 = (lim > 1) ? sflag[p+1] : 0;
      const int f2 = (lim > 2) ? sflag[p+2] : 0;
      const int f3 = (lim > 3) ? sflag[p+3] : 0;
      const float v0 = hsub[(size_t)i0*DIM + t];
      const float v1 = hsub[(size_t)i1*DIM + t];
      const float v2 = hsub[(size_t)i2*DIM + t];
      const float v3 = hsub[(size_t)i3*DIM + t];
      if (f0==1){ sv+=v0; cv++; } else if (f0==2){ sev+=v0; ce++; }
      if (f1==1){ sv+=v1; cv++; } else if (f1==2){ sev+=v1; ce++; }
      if (f2==1){ sv+=v2; cv++; } else if (f2==2){ sev+=v2; ce++; }
      if (f3==1){ sv+=v3; cv++; } else if (f3==2){ sev+=v3; ce++; }
    }
  }
  __syncthreads();
  const float aligned = sv  / fmaxf((float)cv, 1.f);
  const float envv    = sev / fmaxf((float)ce, 1.f);
  float r0 = wave_reduce(aligned*aligned);
  float r1 = wave_reduce(envv*envv);
  float r2 = wave_reduce(aligned != 0.f ? 1.f : 0.f);
  float r3 = wave_reduce(envv    != 0.f ? 1.f : 0.f);
  if (lane == 0){ wr4[w][0]=r0; wr4[w][1]=r1; wr4[w][2]=r2; wr4[w][3]=r3; }
  __syncthreads();
  const float an2  = wr4[0][0]+wr4[1][0]+wr4[2][0]+wr4[3][0];
  const float en2  = wr4[0][1]+wr4[1][1]+wr4[2][1]+wr4[3][1];
  const float nzpf = wr4[0][2]+wr4[1][2]+wr4[2][2]+wr4[3][2];
  const float nzef = wr4[0][3]+wr4[1][3]+wr4[2][3]+wr4[3][3];
  const bool nzp = nzpf > 0.f, nze = nzef > 0.f;
  const float an = fmaxf(sqrtf(an2), 1e-8f);
  const float en = fmaxf(sqrtf(en2), 1e-8f);
  const float ha = aligned / an;
  hatAb[(size_t)g*DIM + t] = (unsigned short)bf16_rne(ha);
  atomicAdd(&S32[((g & (NREP-1)) << 8) + t], ha);
  if (nze) atomicAdd(&Se32[((g & (NREP-1)) << 8) + t], envv / en);
  if (t == 0){
    nzflags[g] = nzp ? 1 : 0;
    if (nzp) atomicAdd(&counters[0], 1);
    if (nze) atomicAdd(&counters[1], 1);
  }
  const float hg = hgraph[(size_t)g*DIM + t];
  #pragma unroll
  for (int c = 0; c < TCLS; ++c){
    float part = hg*Wc[t*TCLS+c] + aligned*Wc[(DIM+t)*TCLS+c];
    part = wave_reduce(part);
    if (lane == 0) wrc[c][w] = part;
  }
  __syncthreads();
  if (t < TCLS)
    out[g*TCLS + t] = wrc[t][0]+wrc[t][1]+wrc[t][2]+wrc[t][3] + bc[t];
}

// ---------------- combine: fold S/Se replicas ----------------
__global__ __launch_bounds__(256) void combine_kernel(const float* __restrict__ S32,
                                                      const float* __restrict__ Se32,
                                                      float* __restrict__ S,
                                                      float* __restrict__ Se){
  const int t = threadIdx.x;
  float s = 0.f, se = 0.f;
  #pragma unroll
  for (int r = 0; r < NREP; ++r){
    s  += S32[r*DIM + t];
    se += Se32[r*DIM + t];
  }
  S[t] = s; Se[t] = se;
}

// ---------------- kernel D: contrastive loss via rank-1 identity ----------------
__global__ __launch_bounds__(256) void loss_kernel(
    const unsigned short* __restrict__ hatAb, const float* __restrict__ S,
    const float* __restrict__ Se, const int* __restrict__ nzflags,
    const int* __restrict__ counters, float* __restrict__ loss_p)
{
  __shared__ float wr[4][2];
  const int g = blockIdx.x, t = threadIdx.x;
  const int w = t >> 6, lane = t & 63;
  const float ha = bf16_to_f((short)hatAb[(size_t)g*DIM + t]);
  float p0 = wave_reduce(ha*S[t]);
  float p1 = wave_reduce(ha*Se[t]);
  if (lane == 0){ wr[w][0] = p0; wr[w][1] = p1; }
  __syncthreads();
  if (t == 0){
    const float dS  = wr[0][0]+wr[1][0]+wr[2][0]+wr[3][0];
    const float dSe = wr[0][1]+wr[1][1]+wr[2][1]+wr[3][1];
    const int nzp_cnt = counters[0];
    const int nenv = counters[1];
    const float pos_num = fmaxf((float)(nzp_cnt - 1), 1.f);
    const float positive = (4096.f - dS) / pos_num;
    const float negative = ((float)nenv - dSe) / fmaxf((float)nenv, 1.f);
    float contrib = fmaxf(positive - negative + 1.f, 0.f);
    contrib *= (nzflags[g] ? 1.f : 0.f) * ((nenv > 0) ? 1.f : 0.f);
    atomicAdd(&loss_p[g & 63], contrib * (1.f/4096.f));
  }
}

// ---------------- final: fold loss partials ----------------
__global__ void final_loss(const float* __restrict__ loss_p, float* __restrict__ loss){
  const int t = threadIdx.x;    // 64 threads
  float v = loss_p[t];
  v = wave_reduce(v);
  if (t == 0) loss[0] = v;
}

// ---------------- launch ----------------
extern "C" void kernel_launch(void* const* d_in, const int* in_sizes, int n_in,
                              void* d_out, int out_size, void* d_ws, size_t ws_size,
                              hipStream_t stream) {
  const float* h_graph = (const float*)d_in[0];
  const float* h_sub   = (const float*)d_in[1];
  const float* W1      = (const float*)d_in[2];
  const float* b1      = (const float*)d_in[3];
  const float* W2      = (const float*)d_in[4];
  const float* b2      = (const float*)d_in[5];
  const float* Wc      = (const float*)d_in[6];
  const float* bc      = (const float*)d_in[7];
  const int*   s2g     = (const int*)d_in[8];

  float* out  = (float*)d_out;          // [4096,10]
  float* loss = out + N_GR*TCLS;        // scalar
  float* mask = loss + 1;               // [200000]

  // workspace layout — ~3.6 MB (proven-safe envelope 5.06 MB)
  char* ws = (char*)d_ws;
  short* bth    = (short*)ws;                          // 256 KB
  short* btl    = bth + HID*DIM;                       // 256 KB
  unsigned short* hatAb = (unsigned short*)(btl + HID*DIM);  // 2 MB
  int* cnt_all  = (int*)(hatAb + (size_t)N_GR*DIM);    // 4096
  int* offs     = cnt_all + N_GR;                      // 4097
  int* cursor   = offs + N_GR + 1;                     // 4096
  int* list     = cursor + N_GR;                       // 200000
  int* nzflags  = list + N_SUB;                        // 4096
  int* counters = nzflags + N_GR;                      // 2
  int* rcnt     = counters + 2;                        // 1
  int* rlist    = rcnt + 1;                            // 16384
  float* S      = (float*)(rlist + RCAP);              // 256
  float* Se     = S + DIM;                             // 256
  float* S32    = Se + DIM;                            // 32*256
  float* Se32   = S32 + NREP*DIM;                      // 32*256
  float* loss_p = Se32 + NREP*DIM;                     // 64

  hipLaunchKernelGGL(bconv_kernel, dim3(HID*DIM/256), dim3(256), 0, stream,
                     W1, bth, btl, cnt_all, S32, Se32, counters, loss_p, rcnt);
  hipLaunchKernelGGL(mask_gemm, dim3(N_SUB/MROWS), dim3(512), 0, stream,
                     h_sub, bth, btl, b1, W2, b2, s2g, mask, cnt_all, rlist, rcnt);
  hipLaunchKernelGGL(refine_kernel, dim3(384), dim3(512), 0, stream,
                     h_sub, W1, b1, W2, b2, rlist, rcnt, mask);
  hipLaunchKernelGGL(scan_kernel, dim3(1), dim3(1024), 0, stream,
                     cnt_all, offs, cursor);
  hipLaunchKernelGGL(fill_kernel, dim3((N_SUB+255)/256), dim3(256), 0, stream,
                     s2g, cursor, list);
  hipLaunchKernelGGL(graph_means, dim3(N_GR), dim3(256), 0, stream,
                     h_sub, mask, list, offs, h_graph, Wc, bc,
                     hatAb, S32, Se32, nzflags, counters, out);
  hipLaunchKernelGGL(combine_kernel, dim3(1), dim3(256), 0, stream,
                     S32, Se32, S, Se);
  hipLaunchKernelGGL(loss_kernel, dim3(N_GR), dim3(256), 0, stream,
                     hatAb, S, Se, nzflags, counters, loss_p);
  hipLaunchKernelGGL(final_loss, dim3(1), dim3(64), 0, stream,
                     loss_p, loss);
}